// Round 2
// baseline (945.239 us; speedup 1.0000x reference)
//
#include <hip/hip_runtime.h>

// Problem constants
#define B_   2048
#define V_   3
#define K_   32
#define DIN_ 256
#define H_   8
#define DH_  64
#define REP_ 512

typedef unsigned short u16;
typedef unsigned int   u32;
typedef __bf16 bf8 __attribute__((ext_vector_type(8)));
typedef float  f4  __attribute__((ext_vector_type(4)));

static __device__ __forceinline__ u16 f2bf(float f) {
  union { float f; u32 i; } x; x.f = f;
  u32 r = (x.i + 0x7FFFu + ((x.i >> 16) & 1u)) >> 16;   // RNE
  return (u16)r;
}
static __device__ __forceinline__ float bf2f(u16 u) {
  union { u32 i; float f; } x; x.i = ((u32)u) << 16;
  return x.f;
}

// ---------------------------------------------------------------------------
// K0: weight prep.
//  nWt/aWt: [v][kt(8)][n(512)][k'(32)] bf16  (K-tiled, transposed: B-operand
//           fragments are 16B-contiguous at ((v*8+kt)*512+n)*32 + lg*8)
//  Wkt/Wvt: [v][h][e(64)][d(64)] bf16 (transposed: B-operand layout)
// ---------------------------------------------------------------------------
__global__ __launch_bounds__(256) void k0_prep(
    const float* __restrict__ nW, const float* __restrict__ aW,
    const float* __restrict__ Wk, const float* __restrict__ Wv,
    u16* __restrict__ nWt, u16* __restrict__ aWt,
    u16* __restrict__ Wkt, u16* __restrict__ Wvt)
{
  int id = blockIdx.x * 256 + threadIdx.x;
  if (id < 393216) {                       // 3*8*512*32
    int v  = id / 131072, r  = id % 131072;
    int kt = r / 16384,   r2 = r % 16384;
    int n  = r2 / 32,     kk = r2 % 32;
    int src = (v * 256 + kt * 32 + kk) * 512 + n;
    nWt[id] = f2bf(nW[src]);
    aWt[id] = f2bf(aW[src]);
  } else {
    int j = id - 393216;                   // < 98304 = 3*8*64*64
    int vh = j / 4096, r = j % 4096;
    int e = r / 64, d = r % 64;
    int src = (vh * 64 + d) * 64 + e;
    Wkt[j] = f2bf(Wk[src]);
    Wvt[j] = f2bf(Wv[src]);
  }
}

// ---------------------------------------------------------------------------
// K1 v2: [64 x 512] = [64 x 256] @ [256 x 512] bf16 MFMA GEMM + bias + LN.
// Changes vs v1: B-operand fragments are loaded DIRECTLY from global (L2-hot
// bf16 weights) inside a barrier-free K loop; LDS is 32 KB (A tile only),
// reused by a two-pass (32 rows each) LayerNorm epilogue.
// mode 0 (neighbors): block = (2 b's x 32 k) for one v; out hn bf16,
//   head-major layout [v][h][b_local][k][64].
// mode 1 (anchor): block = 64 b's for one v; out ha fp32 [b][v][512].
// ---------------------------------------------------------------------------
__global__ __launch_bounds__(512, 4) void k1_gemm_ln(
    const float* __restrict__ X,      // x_neighbors or x_anchor
    const u16*   __restrict__ Wt,     // nWt or aWt (tiled bf16)
    const float* __restrict__ bias,   // nb or ab   [V][512]
    const float* __restrict__ gamma,  // ng or ag
    const float* __restrict__ betap,  // nbeta or abeta
    u16*   __restrict__ hn,           // out (mode 0)
    float* __restrict__ ha,           // out (mode 1)
    int mode, int b0, int Bc)
{
  __shared__ u16 sA[64 * 256];        // 32 KB; reused as S[32][512] in epilogue
  const int v = blockIdx.y, blk = blockIdx.x, t = threadIdx.x;

  // ---- stage A (fp32 -> bf16, swizzled), once ----
  {
    int row = t >> 3;
    int cbase = (t & 7) * 32;
    long grow;
    if (mode == 0) { int b = b0 + blk * 2 + (row >> 5); grow = ((long)(b * 3 + v) * 32 + (row & 31)) * 256; }
    else           { int b = blk * 64 + row;            grow = (long)(b * 3 + v) * 256; }
    const float4* src = (const float4*)(X + grow + cbase);
    int sw = row & 7;
    #pragma unroll
    for (int j = 0; j < 8; ++j) {
      float4 f = src[j];
      int col = cbase + j * 4;
      int c = col >> 3, m = col & 7;
      ushort4 u;
      u.x = f2bf(f.x); u.y = f2bf(f.y); u.z = f2bf(f.z); u.w = f2bf(f.w);
      *(ushort4*)&sA[row * 256 + ((c ^ sw) << 3) + m] = u;
    }
  }
  __syncthreads();

  const int w = t >> 6, l = t & 63, lm = l & 15, lg = l >> 4;
  const int wm = w & 1, wn = w >> 1;
  f4 acc[2][8];
  #pragma unroll
  for (int i = 0; i < 2; ++i)
    #pragma unroll
    for (int j = 0; j < 8; ++j) { f4 z = {0.f, 0.f, 0.f, 0.f}; acc[i][j] = z; }

  // ---- K loop: NO barriers. B frags straight from global (L2-hot). ----
  for (int kt = 0; kt < 8; ++kt) {
    const u16* bbase = Wt + ((long)(v * 8 + kt) * 512 + wn * 128 + lm) * 32 + lg * 8;
    bf8 bv[8];
    #pragma unroll
    for (int tn = 0; tn < 8; ++tn)
      bv[tn] = *(const bf8*)(bbase + tn * 512);      // (tn*16 cols) * 32
    bf8 af[2];
    #pragma unroll
    for (int tm = 0; tm < 2; ++tm) {
      int row = wm * 32 + tm * 16 + lm;
      int c = kt * 4 + lg;
      af[tm] = *(const bf8*)&sA[row * 256 + ((c ^ (row & 7)) << 3)];
    }
    #pragma unroll
    for (int tn = 0; tn < 8; ++tn) {
      acc[0][tn] = __builtin_amdgcn_mfma_f32_16x16x32_bf16(af[0], bv[tn], acc[0][tn], 0, 0, 0);
      acc[1][tn] = __builtin_amdgcn_mfma_f32_16x16x32_bf16(af[1], bv[tn], acc[1][tn], 0, 0, 0);
    }
  }
  __syncthreads();

  // ---- two-pass epilogue: 32 rows per pass through the 32 KB S buffer ----
  u16* S = sA;
  #pragma unroll
  for (int p = 0; p < 2; ++p) {
    if (wm == p) {   // wave-uniform: waves owning rows p*32..p*32+31 dump
      float bcol[8];
      #pragma unroll
      for (int tn = 0; tn < 8; ++tn) bcol[tn] = bias[v * 512 + wn * 128 + tn * 16 + lm];
      #pragma unroll
      for (int tm = 0; tm < 2; ++tm)
        #pragma unroll
        for (int tn = 0; tn < 8; ++tn) {
          int col = wn * 128 + tn * 16 + lm;
          int c = col >> 3, m = col & 7;
          #pragma unroll
          for (int r = 0; r < 4; ++r) {
            int row = tm * 16 + lg * 4 + r;   // row within this 32-row half
            S[row * 512 + ((c ^ (row & 7)) << 3) + m] = f2bf(acc[tm][tn][r] + bcol[tn]);
          }
        }
    }
    __syncthreads();
    // LN over 32 rows: 16 threads per row, 4 chunks of 8 each
    {
      int row = t >> 4, ch = t & 15, sw = row & 7;
      float s1 = 0.f, s2 = 0.f;
      #pragma unroll
      for (int j = 0; j < 4; ++j) {
        int c = j * 16 + ch;
        const u16* p8 = &S[row * 512 + ((c ^ sw) << 3)];
        #pragma unroll
        for (int m = 0; m < 8; ++m) { float x = bf2f(p8[m]); s1 += x; s2 += x * x; }
      }
      #pragma unroll
      for (int d = 1; d < 16; d <<= 1) { s1 += __shfl_xor(s1, d, 64); s2 += __shfl_xor(s2, d, 64); }
      float mu = s1 * (1.f / 512.f);
      float var = s2 * (1.f / 512.f) - mu * mu;
      float rs = rsqrtf(var + 1e-5f);
      #pragma unroll
      for (int j = 0; j < 4; ++j) {
        int c = j * 16 + ch;
        const u16* p8 = &S[row * 512 + ((c ^ sw) << 3)];
        int col0 = c * 8;
        float4 g0 = *(const float4*)&gamma[v * 512 + col0];
        float4 g1 = *(const float4*)&gamma[v * 512 + col0 + 4];
        float4 e0 = *(const float4*)&betap[v * 512 + col0];
        float4 e1 = *(const float4*)&betap[v * 512 + col0 + 4];
        float y0 = (bf2f(p8[0]) - mu) * rs * g0.x + e0.x;
        float y1 = (bf2f(p8[1]) - mu) * rs * g0.y + e0.y;
        float y2 = (bf2f(p8[2]) - mu) * rs * g0.z + e0.z;
        float y3 = (bf2f(p8[3]) - mu) * rs * g0.w + e0.w;
        float y4 = (bf2f(p8[4]) - mu) * rs * g1.x + e1.x;
        float y5 = (bf2f(p8[5]) - mu) * rs * g1.y + e1.y;
        float y6 = (bf2f(p8[6]) - mu) * rs * g1.z + e1.z;
        float y7 = (bf2f(p8[7]) - mu) * rs * g1.w + e1.w;
        if (mode == 0) {
          int head = c >> 3, eo = (c & 7) * 8;
          uint4 q4;
          q4.x = (u32)f2bf(y0) | ((u32)f2bf(y1) << 16);
          q4.y = (u32)f2bf(y2) | ((u32)f2bf(y3) << 16);
          q4.z = (u32)f2bf(y4) | ((u32)f2bf(y5) << 16);
          q4.w = (u32)f2bf(y6) | ((u32)f2bf(y7) << 16);
          u16* dst = hn + (((long)(v * 8 + head) * Bc + (blk * 2 + p)) * 32 + row) * 64 + eo;
          *(uint4*)dst = q4;
        } else {
          int b = blk * 64 + p * 32 + row;
          float* dst = ha + (long)(b * 3 + v) * 512 + col0;
          float4 w0, w1;
          w0.x = y0; w0.y = y1; w0.z = y2; w0.w = y3;
          w1.x = y4; w1.y = y5; w1.z = y6; w1.w = y7;
          *(float4*)dst = w0;
          *(float4*)(dst + 4) = w1;
        }
      }
    }
    __syncthreads();
  }
}

// ---------------------------------------------------------------------------
// K2: per (v, h, group of 8 b's): k/v projections via MFMA, attention in fp32,
// Wo + residual, writes view_tokens [B][H][V][64].
// ---------------------------------------------------------------------------
__global__ __launch_bounds__(256, 2) void k2_attn(
    const u16*   __restrict__ hn,     // [V][H][Bc][K][64] bf16
    const float* __restrict__ ha,     // [B][V][512] f32
    const u16*   __restrict__ Wkt,    // [V][H][64][64] bf16 transposed
    const u16*   __restrict__ Wvt,
    const float* __restrict__ Wq,     // [V][H][64][64] f32
    const float* __restrict__ Wo,
    const float* __restrict__ ew,     // [B][V][K]
    const float* __restrict__ gls,    // [V][H]
    float* __restrict__ vt,           // [B][H][V][64]
    int b0, int Bc)
{
  const int v = blockIdx.z, h = blockIdx.y;
  const int bL0 = blockIdx.x * 8;
  const int t = threadIdx.x;
  __shared__ u16 A[256 * 72];         // hn slice; later Kmat
  __shared__ u16 Wk_s[64 * 72], Wv_s[64 * 72];
  __shared__ float q_s[8 * 64], ha_s[8 * 64], attn_s[8 * 32], o_s[8 * 64];

  // stage hn (32 KB contiguous)
  {
    const uint4* src = (const uint4*)(hn + ((long)(v * 8 + h) * Bc + bL0) * 2048);
    #pragma unroll
    for (int i = 0; i < 8; ++i) {
      uint4 d = src[t * 8 + i];
      *(uint4*)&A[t * 72 + i * 8] = d;
    }
  }
  // stage Wkt/Wvt
  {
    const uint4* sk = (const uint4*)(Wkt + (long)(v * 8 + h) * 4096);
    const uint4* sv = (const uint4*)(Wvt + (long)(v * 8 + h) * 4096);
    #pragma unroll
    for (int i = 0; i < 2; ++i) {
      int idx = i * 256 + t;
      int n = idx >> 3, k8 = (idx & 7) * 8;
      *(uint4*)&Wk_s[n * 72 + k8] = sk[idx];
      *(uint4*)&Wv_s[n * 72 + k8] = sv[idx];
    }
  }
  // stage ha head slice
  #pragma unroll
  for (int i = 0; i < 2; ++i) {
    int idx = i * 256 + t; int b = idx >> 6, e = idx & 63;
    ha_s[idx] = ha[((long)(b0 + bL0 + b) * 3 + v) * 512 + h * 64 + e];
  }
  __syncthreads();

  const int w = t >> 6, l = t & 63, lm = l & 15, lg = l >> 4;
  f4 aK[4][4], aV[4][4];
  #pragma unroll
  for (int i = 0; i < 4; ++i)
    #pragma unroll
    for (int j = 0; j < 4; ++j) { f4 z = {0.f, 0.f, 0.f, 0.f}; aK[i][j] = z; aV[i][j] = z; }

  #pragma unroll
  for (int ks = 0; ks < 2; ++ks) {
    int ko = ks * 32 + lg * 8;
    bf8 af[4];
    #pragma unroll
    for (int tm = 0; tm < 4; ++tm) af[tm] = *(const bf8*)&A[(w * 64 + tm * 16 + lm) * 72 + ko];
    #pragma unroll
    for (int tn = 0; tn < 4; ++tn) {
      bf8 bk = *(const bf8*)&Wk_s[(tn * 16 + lm) * 72 + ko];
      bf8 bv = *(const bf8*)&Wv_s[(tn * 16 + lm) * 72 + ko];
      #pragma unroll
      for (int tm = 0; tm < 4; ++tm) {
        aK[tm][tn] = __builtin_amdgcn_mfma_f32_16x16x32_bf16(af[tm], bk, aK[tm][tn], 0, 0, 0);
        aV[tm][tn] = __builtin_amdgcn_mfma_f32_16x16x32_bf16(af[tm], bv, aV[tm][tn], 0, 0, 0);
      }
    }
  }
  __syncthreads();   // all reads of A done

  // dump Kmat into A; q-projection (fp32)
  #pragma unroll
  for (int tm = 0; tm < 4; ++tm)
    #pragma unroll
    for (int tn = 0; tn < 4; ++tn)
      #pragma unroll
      for (int r = 0; r < 4; ++r) {
        int row = w * 64 + tm * 16 + lg * 4 + r;
        int col = tn * 16 + lm;
        A[row * 72 + col] = f2bf(aK[tm][tn][r]);
      }
  {
    const float* wq = Wq + (long)(v * 8 + h) * 4096;
    #pragma unroll
    for (int i = 0; i < 2; ++i) {
      int idx = i * 256 + t; int b = idx >> 6, e = idx & 63;
      float acc = 0.f;
      for (int d = 0; d < 64; ++d) acc += ha_s[b * 64 + d] * wq[d * 64 + e];
      q_s[idx] = acc * 0.125f;    // 1/sqrt(64)
    }
  }
  __syncthreads();

  // scores + softmax
  {
    int b = t >> 5, k = t & 31;
    float x = gls[v * 8 + h];
    float gsc = (x > 20.f) ? x : log1pf(expf(x));
    float s = 0.f;
    const u16* kr = &A[(b * 32 + k) * 72];
    for (int d = 0; d < 64; ++d) s += q_s[b * 64 + d] * bf2f(kr[d]);
    float e_w = ew[((long)(b0 + bL0 + b) * 3 + v) * 32 + k];
    s += gsc * logf(e_w + 1e-6f);
    float m = s;
    #pragma unroll
    for (int d = 1; d < 32; d <<= 1) m = fmaxf(m, __shfl_xor(m, d, 64));
    float exs = expf(s - m), sum = exs;
    #pragma unroll
    for (int d = 1; d < 32; d <<= 1) sum += __shfl_xor(sum, d, 64);
    attn_s[b * 32 + k] = exs / sum;
  }
  __syncthreads();

  // o = attn @ V, straight from accumulators
  {
    float p[2][4] = {{0.f,0.f,0.f,0.f},{0.f,0.f,0.f,0.f}};
    #pragma unroll
    for (int tm = 0; tm < 4; ++tm) {
      int bh = tm >> 1;
      #pragma unroll
      for (int r = 0; r < 4; ++r) {
        int k = (tm & 1) * 16 + lg * 4 + r;
        float a = attn_s[(w * 2 + bh) * 32 + k];
        #pragma unroll
        for (int tn = 0; tn < 4; ++tn) p[bh][tn] += a * aV[tm][tn][r];
      }
    }
    #pragma unroll
    for (int bh = 0; bh < 2; ++bh)
      #pragma unroll
      for (int tn = 0; tn < 4; ++tn) {
        float x = p[bh][tn];
        x += __shfl_xor(x, 16, 64);
        x += __shfl_xor(x, 32, 64);
        if (l < 16) o_s[(w * 2 + bh) * 64 + tn * 16 + lm] = x;
      }
  }
  __syncthreads();

  // out = o @ Wo + ha (residual), write view_tokens
  {
    const float* wo = Wo + (long)(v * 8 + h) * 4096;
    #pragma unroll
    for (int i = 0; i < 2; ++i) {
      int idx = i * 256 + t; int b = idx >> 6, e = idx & 63;
      float acc = ha_s[b * 64 + e];
      for (int d = 0; d < 64; ++d) acc += o_s[b * 64 + d] * wo[d * 64 + e];
      vt[(((long)(b0 + bL0 + b) * 8 + h) * 3 + v) * 64 + e] = acc;
    }
  }
}

// ---------------------------------------------------------------------------
// K3: router MLP (fp32). Block = 16 b's.
// ---------------------------------------------------------------------------
__global__ __launch_bounds__(256) void k3_router(
    const float* __restrict__ g, const float* __restrict__ rW1, const float* __restrict__ rb1,
    const float* __restrict__ rW2, const float* __restrict__ rb2,
    const float* __restrict__ vW, const float* __restrict__ vb,
    const float* __restrict__ mW, const float* __restrict__ mb,
    const float* __restrict__ gW, const float* __restrict__ gb,
    float* __restrict__ pi, float* __restrict__ beta_o, float* __restrict__ gate_o)
{
  __shared__ float gs[16 * 128], h1[16 * 256], h2[16 * 256], lgt[16 * 40];
  int t = threadIdx.x, bb = blockIdx.x * 16;
  #pragma unroll
  for (int r = 0; r < 8; ++r) { int idx = r * 256 + t; gs[idx] = g[(long)bb * 128 + idx]; }
  __syncthreads();
  {
    int bl = t >> 4, e0 = (t & 15) * 16;
    float acc[16];
    #pragma unroll
    for (int j = 0; j < 16; ++j) acc[j] = rb1[e0 + j];
    for (int i = 0; i < 128; ++i) {
      float gv = gs[bl * 128 + i];
      const float* wr = rW1 + i * 256 + e0;
      #pragma unroll
      for (int j = 0; j < 16; ++j) acc[j] += gv * wr[j];
    }
    #pragma unroll
    for (int j = 0; j < 16; ++j) { float x = acc[j]; h1[bl * 256 + e0 + j] = 0.5f * x * (1.f + erff(x * 0.70710678118f)); }
  }
  __syncthreads();
  {
    int bl = t >> 4, e0 = (t & 15) * 16;
    float acc[16];
    #pragma unroll
    for (int j = 0; j < 16; ++j) acc[j] = rb2[e0 + j];
    for (int i = 0; i < 256; ++i) {
      float hv = h1[bl * 256 + i];
      const float* wr = rW2 + i * 256 + e0;
      #pragma unroll
      for (int j = 0; j < 16; ++j) acc[j] += hv * wr[j];
    }
    #pragma unroll
    for (int j = 0; j < 16; ++j) { float x = acc[j]; h2[bl * 256 + e0 + j] = 0.5f * x * (1.f + erff(x * 0.70710678118f)); }
  }
  __syncthreads();
  for (int idx = t; idx < 640; idx += 256) {
    int bl = idx / 40, j = idx % 40;
    const float* W; float bs; int col, stride;
    if (j < 24)      { W = vW; col = j;      stride = 24; bs = vb[j]; }
    else if (j < 32) { W = mW; col = j - 24; stride = 8;  bs = mb[j - 24]; }
    else             { W = gW; col = j - 32; stride = 8;  bs = gb[j - 32]; }
    float acc = bs;
    for (int i = 0; i < 256; ++i) acc += h2[bl * 256 + i] * W[i * stride + col];
    lgt[bl * 40 + j] = acc;
  }
  __syncthreads();
  if (t < 16) {
    int b = bb + t;
    const float* L = &lgt[t * 40];
    #pragma unroll
    for (int hh = 0; hh < 8; ++hh) {
      float a0 = L[hh * 3], a1 = L[hh * 3 + 1], a2v = L[hh * 3 + 2];
      float m = fmaxf(a0, fmaxf(a1, a2v));
      float x0 = expf(a0 - m), x1 = expf(a1 - m), x2 = expf(a2v - m);
      float inv = 1.f / (x0 + x1 + x2);
      pi[b * 24 + hh * 3 + 0] = x0 * inv;
      pi[b * 24 + hh * 3 + 1] = x1 * inv;
      pi[b * 24 + hh * 3 + 2] = x2 * inv;
      beta_o[b * 8 + hh] = 1.f / (1.f + expf(-L[24 + hh]));
    }
    float m = L[32];
    #pragma unroll
    for (int hh = 1; hh < 8; ++hh) m = fmaxf(m, L[32 + hh]);
    float s = 0.f, ex[8];
    #pragma unroll
    for (int hh = 0; hh < 8; ++hh) { ex[hh] = expf(L[32 + hh] - m); s += ex[hh]; }
    float inv = 1.f / s;
    #pragma unroll
    for (int hh = 0; hh < 8; ++hh) gate_o[b * 8 + hh] = ex[hh] * inv;
  }
}

// ---------------------------------------------------------------------------
// K4: pi-mixture + cross-view attention + output. Block = 4 b's, fp32.
// kc/vc never materialized:  s2 = (qc @ cWk^T) . vt ;  cr = (sum_v a2*vt) @ cWv.
// ---------------------------------------------------------------------------
__global__ __launch_bounds__(256) void k4_cross(
    const float* __restrict__ vtg, const float* __restrict__ pig,
    const float* __restrict__ betag, const float* __restrict__ gateg,
    const float* __restrict__ cWq, const float* __restrict__ cWk,
    const float* __restrict__ cWv, const float* __restrict__ cWo,
    float* __restrict__ out)
{
  __shared__ float smem[12544];
  float* vts   = smem;          // 6144: [4][8][3][64]
  float* mixs  = smem + 6144;   // 2048
  float* buf1  = smem + 8192;   // 2048: qc, then y
  float* buf2  = smem + 10240;  // 2048: w,  then cr
  float* a2s   = smem + 12288;  // 96
  float* pis   = smem + 12384;  // 96
  float* betas = smem + 12480;  // 32
  float* gates = smem + 12512;  // 32

  int t = threadIdx.x, bblk = blockIdx.x * 4;
  {
    const float4* src = (const float4*)(vtg + (long)bblk * 1536);
    #pragma unroll
    for (int r = 0; r < 6; ++r) ((float4*)vts)[r * 256 + t] = src[r * 256 + t];
    if (t < 96) pis[t] = pig[bblk * 24 + t];
    if (t < 32) { betas[t] = betag[bblk * 8 + t]; gates[t] = gateg[bblk * 8 + t]; }
  }
  __syncthreads();
  int bl = t >> 6, hh = (t >> 3) & 7, e0 = (t & 7) * 8;
  const float* vbh = &vts[(bl * 8 + hh) * 192];
  { // mix
    float p0 = pis[bl * 24 + hh * 3], p1 = pis[bl * 24 + hh * 3 + 1], p2 = pis[bl * 24 + hh * 3 + 2];
    #pragma unroll
    for (int j = 0; j < 8; ++j) {
      int e = e0 + j;
      mixs[(bl * 8 + hh) * 64 + e] = p0 * vbh[e] + p1 * vbh[64 + e] + p2 * vbh[128 + e];
    }
  }
  __syncthreads();
  { // qc (scaled by 1/8) -> buf1
    float acc[8] = {0.f,0.f,0.f,0.f,0.f,0.f,0.f,0.f};
    const float* M = &mixs[(bl * 8 + hh) * 64];
    for (int d = 0; d < 64; ++d) {
      float mv = M[d];
      const float* wr = &cWq[(hh * 64 + d) * 64 + e0];
      #pragma unroll
      for (int j = 0; j < 8; ++j) acc[j] += mv * wr[j];
    }
    #pragma unroll
    for (int j = 0; j < 8; ++j) buf1[(bl * 8 + hh) * 64 + e0 + j] = acc[j] * 0.125f;
  }
  __syncthreads();
  { // w = cWk @ qc -> buf2
    const float* Q = &buf1[(bl * 8 + hh) * 64];
    #pragma unroll
    for (int d2 = 0; d2 < 8; ++d2) {
      const float* wr = &cWk[(hh * 64 + e0 + d2) * 64];
      float a = 0.f;
      for (int e = 0; e < 64; ++e) a += wr[e] * Q[e];
      buf2[(bl * 8 + hh) * 64 + e0 + d2] = a;
    }
  }
  __syncthreads();
  if (t < 32) { // s2 + a2
    int b2 = t >> 3, h2 = t & 7;
    const float* Wd = &buf2[(b2 * 8 + h2) * 64];
    const float* vb2 = &vts[(b2 * 8 + h2) * 192];
    float s[3];
    #pragma unroll
    for (int v3 = 0; v3 < 3; ++v3) {
      float a = 0.f;
      for (int d = 0; d < 64; ++d) a += Wd[d] * vb2[v3 * 64 + d];
      s[v3] = a + logf(pis[b2 * 24 + h2 * 3 + v3] + 1e-6f);
    }
    float m = fmaxf(s[0], fmaxf(s[1], s[2]));
    float x0 = expf(s[0] - m), x1 = expf(s[1] - m), x2 = expf(s[2] - m);
    float inv = 1.f / (x0 + x1 + x2);
    a2s[(b2 * 8 + h2) * 3 + 0] = x0 * inv;
    a2s[(b2 * 8 + h2) * 3 + 1] = x1 * inv;
    a2s[(b2 * 8 + h2) * 3 + 2] = x2 * inv;
  }
  __syncthreads();
  { // y = sum_v a2*vt -> buf1 (qc dead)
    float a0 = a2s[(bl * 8 + hh) * 3], a1 = a2s[(bl * 8 + hh) * 3 + 1], a2v = a2s[(bl * 8 + hh) * 3 + 2];
    #pragma unroll
    for (int j = 0; j < 8; ++j) {
      int e = e0 + j;
      buf1[(bl * 8 + hh) * 64 + e] = a0 * vbh[e] + a1 * vbh[64 + e] + a2v * vbh[128 + e];
    }
  }
  __syncthreads();
  { // cr = y @ cWv -> buf2 (w dead)
    float acc[8] = {0.f,0.f,0.f,0.f,0.f,0.f,0.f,0.f};
    const float* Y = &buf1[(bl * 8 + hh) * 64];
    for (int d = 0; d < 64; ++d) {
      float yv = Y[d];
      const float* wr = &cWv[(hh * 64 + d) * 64 + e0];
      #pragma unroll
      for (int j = 0; j < 8; ++j) acc[j] += yv * wr[j];
    }
    #pragma unroll
    for (int j = 0; j < 8; ++j) buf2[(bl * 8 + hh) * 64 + e0 + j] = acc[j];
  }
  __syncthreads();
  { // out = gate*(beta*(cr@cWo) + (1-beta)*mix)
    float acc[8] = {0.f,0.f,0.f,0.f,0.f,0.f,0.f,0.f};
    const float* C2 = &buf2[(bl * 8 + hh) * 64];
    for (int d = 0; d < 64; ++d) {
      float cv = C2[d];
      const float* wr = &cWo[(hh * 64 + d) * 64 + e0];
      #pragma unroll
      for (int j = 0; j < 8; ++j) acc[j] += cv * wr[j];
    }
    float bt = betas[bl * 8 + hh], gt = gates[bl * 8 + hh];
    const float* M = &mixs[(bl * 8 + hh) * 64];
    #pragma unroll
    for (int j = 0; j < 8; ++j)
      out[((long)(bblk + bl) * 8 + hh) * 64 + e0 + j] = gt * (bt * acc[j] + (1.f - bt) * M[e0 + j]);
  }
}

// ---------------------------------------------------------------------------
extern "C" void kernel_launch(void* const* d_in, const int* in_sizes, int n_in,
                              void* d_out, int out_size, void* d_ws, size_t ws_size,
                              hipStream_t stream) {
  const float* x_anchor    = (const float*)d_in[0];
  const float* x_neighbors = (const float*)d_in[1];
  const float* edge_w      = (const float*)d_in[2];
  const float* g           = (const float*)d_in[3];
  const float* aW  = (const float*)d_in[4];
  const float* ab  = (const float*)d_in[5];
  const float* ag  = (const float*)d_in[6];
  const float* abeta = (const float*)d_in[7];
  const float* nW  = (const float*)d_in[8];
  const float* nb  = (const float*)d_in[9];
  const float* ng  = (const float*)d_in[10];
  const float* nbeta = (const float*)d_in[11];
  const float* Wq  = (const float*)d_in[12];
  const float* Wk  = (const float*)d_in[13];
  const float* Wv  = (const float*)d_in[14];
  const float* Wo  = (const float*)d_in[15];
  const float* gls = (const float*)d_in[16];
  const float* cWq = (const float*)d_in[17];
  const float* cWk = (const float*)d_in[18];
  const float* cWv = (const float*)d_in[19];
  const float* cWo = (const float*)d_in[20];
  const float* rW1 = (const float*)d_in[21];
  const float* rb1 = (const float*)d_in[22];
  const float* rW2 = (const float*)d_in[23];
  const float* rb2 = (const float*)d_in[24];
  const float* vW  = (const float*)d_in[25];
  const float* vb  = (const float*)d_in[26];
  const float* mW  = (const float*)d_in[27];
  const float* mb  = (const float*)d_in[28];
  const float* gW  = (const float*)d_in[29];
  const float* gb  = (const float*)d_in[30];

  // workspace carve-up
  char* p = (char*)d_ws;
  u16* nWt = (u16*)p;  p += 786432;
  u16* aWt = (u16*)p;  p += 786432;
  u16* Wkt = (u16*)p;  p += 196608;
  u16* Wvt = (u16*)p;  p += 196608;
  float* ha   = (float*)p; p += 12582912;
  float* vtb  = (float*)p; p += 12582912;
  float* pib  = (float*)p; p += 196608;
  float* betb = (float*)p; p += 65536;
  float* gatb = (float*)p; p += 65536;
  size_t fixed = (size_t)(p - (char*)d_ws);
  // chunking over b so the hn intermediate (bf16, 98304 B per b) fits in ws
  int C = 1;
  while (C < 128 && fixed + (size_t)(2048 / C) * 98304 > ws_size) C <<= 1;
  int Bc = 2048 / C;
  u16* hnb = (u16*)p;

  k0_prep<<<1920, 256, 0, stream>>>(nW, aW, Wk, Wv, nWt, aWt, Wkt, Wvt);
  // anchor encoder: ha (fp32)
  k1_gemm_ln<<<dim3(32, 3), 512, 0, stream>>>(x_anchor, aWt, ab, ag, abeta,
                                              (u16*)nullptr, ha, 1, 0, Bc);
  k3_router<<<128, 256, 0, stream>>>(g, rW1, rb1, rW2, rb2, vW, vb, mW, mb, gW, gb,
                                     pib, betb, gatb);
  for (int c = 0; c < C; ++c) {
    int b0 = c * Bc;
    k1_gemm_ln<<<dim3(Bc / 2, 3), 512, 0, stream>>>(x_neighbors, nWt, nb, ng, nbeta,
                                                    hnb, (float*)nullptr, 0, b0, Bc);
    k2_attn<<<dim3(Bc / 8, 8, 3), 256, 0, stream>>>(hnb, ha, Wkt, Wvt, Wq, Wo,
                                                    edge_w, gls, vtb, b0, Bc);
  }
  k4_cross<<<512, 256, 0, stream>>>(vtb, pib, betb, gatb, cWq, cWk, cWv, cWo,
                                    (float*)d_out);
}

// Round 3
// 784.650 us; speedup vs baseline: 1.2047x; 1.2047x over previous
//
#include <hip/hip_runtime.h>

// Problem constants
#define B_   2048
#define V_   3
#define K_   32
#define DIN_ 256
#define H_   8
#define DH_  64
#define REP_ 512

typedef unsigned short u16;
typedef unsigned int   u32;
typedef __bf16 bf8 __attribute__((ext_vector_type(8)));
typedef float  f4  __attribute__((ext_vector_type(4)));

static __device__ __forceinline__ u16 f2bf(float f) {
  union { float f; u32 i; } x; x.f = f;
  u32 r = (x.i + 0x7FFFu + ((x.i >> 16) & 1u)) >> 16;   // RNE
  return (u16)r;
}
static __device__ __forceinline__ float bf2f(u16 u) {
  union { u32 i; float f; } x; x.i = ((u32)u) << 16;
  return x.f;
}

// async global->LDS DMA, 16 B per lane; lane i lands at lds + i*16
static __device__ __forceinline__ void gl2lds16(const u16* g, u16* l) {
  __builtin_amdgcn_global_load_lds(
      (const __attribute__((address_space(1))) unsigned int*)(g),
      (__attribute__((address_space(3))) unsigned int*)(l), 16, 0, 0);
}
// wait all vm loads (incl. global_load_lds DMA) then workgroup barrier —
// WITHOUT the compiler's full lgkm/exp drain, and without letting it
// reorder memory ops across.
#define ASYNC_BARRIER() asm volatile("s_waitcnt vmcnt(0)\n\ts_barrier" ::: "memory")

// ---------------------------------------------------------------------------
// K0: weight prep.
//  nWt/aWt: [v][kt(8)] x 32KB "LDS image": element at hw index
//    n*32 + (c ^ ((n>>1)&3))*8 + m   equals  W[k = kt*32 + c*8 + m][n]  (bf16)
//  so global_load_lds with linear lane mapping reproduces the swizzled LDS
//  layout the MFMA B-fragment reads expect.
//  Wkt/Wvt: [v][h][e(64)][d(64)] bf16 (transposed: B-operand layout)
// ---------------------------------------------------------------------------
__global__ __launch_bounds__(256) void k0_prep(
    const float* __restrict__ nW, const float* __restrict__ aW,
    const float* __restrict__ Wk, const float* __restrict__ Wv,
    u16* __restrict__ nWt, u16* __restrict__ aWt,
    u16* __restrict__ Wkt, u16* __restrict__ Wvt)
{
  int id = blockIdx.x * 256 + threadIdx.x;
  if (id < 393216) {                       // 3*8*512*32
    int v  = id / 131072, r  = id % 131072;
    int kt = r / 16384,   r2 = r % 16384;
    int n  = r2 >> 5;
    int s  = (r2 >> 3) & 3;
    int m  = r2 & 7;
    int c  = s ^ ((n >> 1) & 3);
    int k  = kt * 32 + c * 8 + m;
    int src = (v * 256 + k) * 512 + n;
    nWt[id] = f2bf(nW[src]);
    aWt[id] = f2bf(aW[src]);
  } else {
    int j = id - 393216;                   // < 98304 = 3*8*64*64
    int vh = j / 4096, r = j % 4096;
    int e = r / 64, d = r % 64;
    int src = (vh * 64 + d) * 64 + e;
    Wkt[j] = f2bf(Wk[src]);
    Wvt[j] = f2bf(Wv[src]);
  }
}

// ---------------------------------------------------------------------------
// K1 v3: [32 x 512] = [32 x 256] @ [256 x 512] bf16 MFMA GEMM + bias + LN.
// Double-buffered async B staging via global_load_lds (pre-swizzled image),
// ONE barrier per kt, prefetch issued a full compute block ahead.
// LDS: A 16 KB + B dbuf 2x32 KB = 80 KB (S 32x512 bf16 overlays B) ->
// 2 blocks/CU. 256 threads = 4 waves, each owns 128 N-cols.
// mode 0 (neighbors): block = 1 b (32 k rows) for one v; out hn bf16
//   head-major [v][h][b_local][k][64].
// mode 1 (anchor): block = 32 b's for one v; out ha fp32 [b][v][512].
// ---------------------------------------------------------------------------
__global__ __launch_bounds__(256, 2) void k1_gemm_ln(
    const float* __restrict__ X,      // x_neighbors or x_anchor
    const u16*   __restrict__ Wt,     // nWt or aWt (swizzled LDS-image tiles)
    const float* __restrict__ bias,   // nb or ab   [V][512]
    const float* __restrict__ gamma,  // ng or ag
    const float* __restrict__ betap,  // nbeta or abeta
    u16*   __restrict__ hn,           // out (mode 0)
    float* __restrict__ ha,           // out (mode 1)
    int mode, int b0, int Bc)
{
  __shared__ u16 sA[32 * 256];        // 16 KB
  __shared__ u16 sB[2][16384];        // 2 x 32 KB; epilogue S overlays sB[0..1]
  const int v = blockIdx.y, blk = blockIdx.x, t = threadIdx.x;
  const int w = t >> 6, l = t & 63, lm = l & 15, lg = l >> 4;

  // bias columns for this wave's 128-col slice (loads overlap A staging)
  float bcol[8];
  #pragma unroll
  for (int tn = 0; tn < 8; ++tn) bcol[tn] = bias[v * 512 + w * 128 + tn * 16 + lm];

  // ---- stage A (fp32 -> bf16, swizzled), once ----
  {
    int row = t >> 3;
    int cbase = (t & 7) * 32;
    long grow;
    if (mode == 0) { int b = b0 + blk; grow = ((long)(b * 3 + v) * 32 + row) * 256; }
    else           { int b = blk * 32 + row; grow = (long)(b * 3 + v) * 256; }
    const float4* src = (const float4*)(X + grow + cbase);
    int sw = row & 7;
    #pragma unroll
    for (int j = 0; j < 8; ++j) {
      float4 f = src[j];
      int col = cbase + j * 4;
      int c = col >> 3, m = col & 7;
      ushort4 u;
      u.x = f2bf(f.x); u.y = f2bf(f.y); u.z = f2bf(f.z); u.w = f2bf(f.w);
      *(ushort4*)&sA[row * 256 + ((c ^ sw) << 3) + m] = u;
    }
  }

  // ---- prefetch B tile kt=0 into buffer 0 (async DMA) ----
  const u16* Wbase = Wt + (long)v * 8 * 16384;
  {
    const u16* gp = Wbase + w * 4096 + l * 8;
    u16* lp = &sB[0][w * 4096];
    #pragma unroll
    for (int j = 0; j < 8; ++j) gl2lds16(gp + j * 512, lp + j * 512);
  }
  __syncthreads();   // drains vmcnt(0): kt0 B ready; lgkm: A ready

  f4 acc[2][8];
  #pragma unroll
  for (int i = 0; i < 2; ++i)
    #pragma unroll
    for (int j = 0; j < 8; ++j) { f4 z = {0.f, 0.f, 0.f, 0.f}; acc[i][j] = z; }

  // ---- K loop: one barrier per kt, DMA prefetch a full block ahead ----
  #pragma unroll
  for (int kt = 0; kt < 8; ++kt) {
    if (kt < 7) {   // issue next tile's DMA before computing current
      const u16* gp = Wbase + (kt + 1) * 16384 + w * 4096 + l * 8;
      u16* lp = &sB[(kt + 1) & 1][w * 4096];
      #pragma unroll
      for (int j = 0; j < 8; ++j) gl2lds16(gp + j * 512, lp + j * 512);
    }
    const u16* Bcur = &sB[kt & 1][0];
    bf8 af[2];
    #pragma unroll
    for (int tm = 0; tm < 2; ++tm) {
      int row = tm * 16 + lm;
      int c = kt * 4 + lg;
      af[tm] = *(const bf8*)&sA[row * 256 + ((c ^ (row & 7)) << 3)];
    }
    #pragma unroll
    for (int tn = 0; tn < 8; ++tn) {
      int n = w * 128 + tn * 16 + lm;
      bf8 bv = *(const bf8*)&Bcur[n * 32 + ((lg ^ ((n >> 1) & 3)) << 3)];
      acc[0][tn] = __builtin_amdgcn_mfma_f32_16x16x32_bf16(af[0], bv, acc[0][tn], 0, 0, 0);
      acc[1][tn] = __builtin_amdgcn_mfma_f32_16x16x32_bf16(af[1], bv, acc[1][tn], 0, 0, 0);
    }
    if (kt < 7) ASYNC_BARRIER();   // next tile arrived (latency hidden by MFMAs);
                                   // all waves done reading current buffer
  }
  __syncthreads();

  // ---- dump z = acc + bias into S (32x512 bf16, swizzled; overlays sB) ----
  u16* S = &sB[0][0];
  #pragma unroll
  for (int tm = 0; tm < 2; ++tm)
    #pragma unroll
    for (int tn = 0; tn < 8; ++tn) {
      int col = w * 128 + tn * 16 + lm;
      int c = col >> 3, m = col & 7;
      #pragma unroll
      for (int r = 0; r < 4; ++r) {
        int row = tm * 16 + lg * 4 + r;
        S[row * 512 + ((c ^ (row & 7)) << 3) + m] = f2bf(acc[tm][tn][r] + bcol[tn]);
      }
    }
  __syncthreads();

  // ---- LayerNorm + writeout: 8 threads/row, 8 chunks of 8 each ----
  {
    int row = t >> 3, ch = t & 7, sw = row & 7;
    float s1 = 0.f, s2 = 0.f;
    #pragma unroll
    for (int j = 0; j < 8; ++j) {
      int c = j * 8 + ch;
      const u16* p8 = &S[row * 512 + ((c ^ sw) << 3)];
      #pragma unroll
      for (int m = 0; m < 8; ++m) { float x = bf2f(p8[m]); s1 += x; s2 += x * x; }
    }
    #pragma unroll
    for (int d = 1; d < 8; d <<= 1) { s1 += __shfl_xor(s1, d, 64); s2 += __shfl_xor(s2, d, 64); }
    float mu = s1 * (1.f / 512.f);
    float var = s2 * (1.f / 512.f) - mu * mu;
    float rs = rsqrtf(var + 1e-5f);
    #pragma unroll
    for (int j = 0; j < 8; ++j) {
      int c = j * 8 + ch;
      const u16* p8 = &S[row * 512 + ((c ^ sw) << 3)];
      int col0 = c * 8;
      float4 g0 = *(const float4*)&gamma[v * 512 + col0];
      float4 g1 = *(const float4*)&gamma[v * 512 + col0 + 4];
      float4 e0 = *(const float4*)&betap[v * 512 + col0];
      float4 e1 = *(const float4*)&betap[v * 512 + col0 + 4];
      float y0 = (bf2f(p8[0]) - mu) * rs * g0.x + e0.x;
      float y1 = (bf2f(p8[1]) - mu) * rs * g0.y + e0.y;
      float y2 = (bf2f(p8[2]) - mu) * rs * g0.z + e0.z;
      float y3 = (bf2f(p8[3]) - mu) * rs * g0.w + e0.w;
      float y4 = (bf2f(p8[4]) - mu) * rs * g1.x + e1.x;
      float y5 = (bf2f(p8[5]) - mu) * rs * g1.y + e1.y;
      float y6 = (bf2f(p8[6]) - mu) * rs * g1.z + e1.z;
      float y7 = (bf2f(p8[7]) - mu) * rs * g1.w + e1.w;
      if (mode == 0) {
        // j == head, ch*8 == element offset within head
        uint4 q4;
        q4.x = (u32)f2bf(y0) | ((u32)f2bf(y1) << 16);
        q4.y = (u32)f2bf(y2) | ((u32)f2bf(y3) << 16);
        q4.z = (u32)f2bf(y4) | ((u32)f2bf(y5) << 16);
        q4.w = (u32)f2bf(y6) | ((u32)f2bf(y7) << 16);
        u16* dst = hn + (((long)(v * 8 + j) * Bc + blk) * 32 + row) * 64 + ch * 8;
        *(uint4*)dst = q4;
      } else {
        int b = blk * 32 + row;
        float* dst = ha + (long)(b * 3 + v) * 512 + col0;
        float4 w0, w1;
        w0.x = y0; w0.y = y1; w0.z = y2; w0.w = y3;
        w1.x = y4; w1.y = y5; w1.z = y6; w1.w = y7;
        *(float4*)dst = w0;
        *(float4*)(dst + 4) = w1;
      }
    }
  }
}

// ---------------------------------------------------------------------------
// K2 v2: per (v, h, group of 4 b's): k/v projections via MFMA (1 b per wave),
// attention in fp32, Wo + residual, writes view_tokens [B][H][V][64].
// LDS ~40 KB -> 3 blocks/CU; 2x blocks vs v1.
// ---------------------------------------------------------------------------
__global__ __launch_bounds__(256, 2) void k2_attn(
    const u16*   __restrict__ hn,     // [V][H][Bc][K][64] bf16
    const float* __restrict__ ha,     // [B][V][512] f32
    const u16*   __restrict__ Wkt,    // [V][H][64][64] bf16 transposed
    const u16*   __restrict__ Wvt,
    const float* __restrict__ Wq,     // [V][H][64][64] f32
    const float* __restrict__ Wo,
    const float* __restrict__ ew,     // [B][V][K]
    const float* __restrict__ gls,    // [V][H]
    float* __restrict__ vt,           // [B][H][V][64]
    int b0, int Bc)
{
  const int v = blockIdx.z, h = blockIdx.y;
  const int bL0 = blockIdx.x * 4;
  const int t = threadIdx.x;
  __shared__ u16 A[128 * 72];         // hn slice (4b x 32k rows); later Kmat
  __shared__ u16 Wk_s[64 * 72], Wv_s[64 * 72];
  __shared__ float q_s[4 * 64], ha_s[4 * 64], attn_s[4 * 32], o_s[4 * 64];

  // stage hn (16 KB contiguous): 128 rows x 64 d
  {
    const uint4* src = (const uint4*)(hn + ((long)(v * 8 + h) * Bc + bL0) * 2048);
    int r = t >> 1, half = t & 1;
    #pragma unroll
    for (int i = 0; i < 4; ++i) {
      uint4 d = src[r * 8 + half * 4 + i];
      *(uint4*)&A[r * 72 + half * 32 + i * 8] = d;
    }
  }
  // stage Wkt/Wvt
  {
    const uint4* sk = (const uint4*)(Wkt + (long)(v * 8 + h) * 4096);
    const uint4* sv = (const uint4*)(Wvt + (long)(v * 8 + h) * 4096);
    #pragma unroll
    for (int i = 0; i < 2; ++i) {
      int idx = i * 256 + t;
      int n = idx >> 3, k8 = (idx & 7) * 8;
      *(uint4*)&Wk_s[n * 72 + k8] = sk[idx];
      *(uint4*)&Wv_s[n * 72 + k8] = sv[idx];
    }
  }
  // stage ha head slice (4 b x 64 e)
  {
    int b = t >> 6, e = t & 63;
    ha_s[t] = ha[((long)(b0 + bL0 + b) * 3 + v) * 512 + h * 64 + e];
  }
  __syncthreads();

  const int w = t >> 6, l = t & 63, lm = l & 15, lg = l >> 4;
  f4 aK[2][4], aV[2][4];
  #pragma unroll
  for (int i = 0; i < 2; ++i)
    #pragma unroll
    for (int j = 0; j < 4; ++j) { f4 z = {0.f, 0.f, 0.f, 0.f}; aK[i][j] = z; aV[i][j] = z; }

  // wave w owns b = w (rows w*32 .. w*32+31)
  #pragma unroll
  for (int ks = 0; ks < 2; ++ks) {
    int ko = ks * 32 + lg * 8;
    bf8 af[2];
    #pragma unroll
    for (int tm = 0; tm < 2; ++tm) af[tm] = *(const bf8*)&A[(w * 32 + tm * 16 + lm) * 72 + ko];
    #pragma unroll
    for (int tn = 0; tn < 4; ++tn) {
      bf8 bk = *(const bf8*)&Wk_s[(tn * 16 + lm) * 72 + ko];
      bf8 bv = *(const bf8*)&Wv_s[(tn * 16 + lm) * 72 + ko];
      #pragma unroll
      for (int tm = 0; tm < 2; ++tm) {
        aK[tm][tn] = __builtin_amdgcn_mfma_f32_16x16x32_bf16(af[tm], bk, aK[tm][tn], 0, 0, 0);
        aV[tm][tn] = __builtin_amdgcn_mfma_f32_16x16x32_bf16(af[tm], bv, aV[tm][tn], 0, 0, 0);
      }
    }
  }
  __syncthreads();   // all reads of A done

  // dump Kmat into A; q-projection (fp32)
  #pragma unroll
  for (int tm = 0; tm < 2; ++tm)
    #pragma unroll
    for (int tn = 0; tn < 4; ++tn)
      #pragma unroll
      for (int r = 0; r < 4; ++r) {
        int row = w * 32 + tm * 16 + lg * 4 + r;
        int col = tn * 16 + lm;
        A[row * 72 + col] = f2bf(aK[tm][tn][r]);
      }
  {
    const float* wq = Wq + (long)(v * 8 + h) * 4096;
    int b = t >> 6, e = t & 63;
    float acc = 0.f;
    for (int d = 0; d < 64; ++d) acc += ha_s[b * 64 + d] * wq[d * 64 + e];
    q_s[t] = acc * 0.125f;    // 1/sqrt(64)
  }
  __syncthreads();

  // scores + softmax (4 b x 32 k = 128 threads)
  if (t < 128) {
    int b = t >> 5, k = t & 31;
    float x = gls[v * 8 + h];
    float gsc = (x > 20.f) ? x : log1pf(expf(x));
    float s = 0.f;
    const u16* kr = &A[(b * 32 + k) * 72];
    for (int d = 0; d < 64; ++d) s += q_s[b * 64 + d] * bf2f(kr[d]);
    float e_w = ew[((long)(b0 + bL0 + b) * 3 + v) * 32 + k];
    s += gsc * logf(e_w + 1e-6f);
    float m = s;
    #pragma unroll
    for (int d = 1; d < 32; d <<= 1) m = fmaxf(m, __shfl_xor(m, d, 64));
    float exs = expf(s - m), sum = exs;
    #pragma unroll
    for (int d = 1; d < 32; d <<= 1) sum += __shfl_xor(sum, d, 64);
    attn_s[b * 32 + k] = exs / sum;
  }
  __syncthreads();

  // o = attn @ V, straight from accumulators (wave w -> b = w)
  {
    float p[4] = {0.f, 0.f, 0.f, 0.f};
    #pragma unroll
    for (int tm = 0; tm < 2; ++tm)
      #pragma unroll
      for (int r = 0; r < 4; ++r) {
        int k = tm * 16 + lg * 4 + r;
        float a = attn_s[w * 32 + k];
        #pragma unroll
        for (int tn = 0; tn < 4; ++tn) p[tn] += a * aV[tm][tn][r];
      }
    #pragma unroll
    for (int tn = 0; tn < 4; ++tn) {
      float x = p[tn];
      x += __shfl_xor(x, 16, 64);
      x += __shfl_xor(x, 32, 64);
      if (l < 16) o_s[w * 64 + tn * 16 + lm] = x;
    }
  }
  __syncthreads();

  // out = o @ Wo + ha (residual), write view_tokens
  {
    const float* wo = Wo + (long)(v * 8 + h) * 4096;
    int b = t >> 6, e = t & 63;
    float acc = ha_s[b * 64 + e];
    for (int d = 0; d < 64; ++d) acc += o_s[b * 64 + d] * wo[d * 64 + e];
    vt[(((long)(b0 + bL0 + b) * 8 + h) * 3 + v) * 64 + e] = acc;
  }
}

// ---------------------------------------------------------------------------
// K3 v2: router MLP (fp32). Block = 4 b's (512 blocks -> full GPU).
// ---------------------------------------------------------------------------
__global__ __launch_bounds__(256) void k3_router(
    const float* __restrict__ g, const float* __restrict__ rW1, const float* __restrict__ rb1,
    const float* __restrict__ rW2, const float* __restrict__ rb2,
    const float* __restrict__ vW, const float* __restrict__ vb,
    const float* __restrict__ mW, const float* __restrict__ mb,
    const float* __restrict__ gW, const float* __restrict__ gb,
    float* __restrict__ pi, float* __restrict__ beta_o, float* __restrict__ gate_o)
{
  __shared__ float gs[4 * 128], h1[4 * 256], h2[4 * 256], lgt[4 * 40];
  int t = threadIdx.x, bb = blockIdx.x * 4;
  #pragma unroll
  for (int r = 0; r < 2; ++r) { int idx = r * 256 + t; gs[idx] = g[(long)bb * 128 + idx]; }
  __syncthreads();
  {
    int bl = t >> 6, e0 = (t & 63) * 4;
    float acc[4];
    #pragma unroll
    for (int j = 0; j < 4; ++j) acc[j] = rb1[e0 + j];
    for (int i = 0; i < 128; ++i) {
      float gv = gs[bl * 128 + i];
      const float* wr = rW1 + i * 256 + e0;
      #pragma unroll
      for (int j = 0; j < 4; ++j) acc[j] += gv * wr[j];
    }
    #pragma unroll
    for (int j = 0; j < 4; ++j) { float x = acc[j]; h1[bl * 256 + e0 + j] = 0.5f * x * (1.f + erff(x * 0.70710678118f)); }
  }
  __syncthreads();
  {
    int bl = t >> 6, e0 = (t & 63) * 4;
    float acc[4];
    #pragma unroll
    for (int j = 0; j < 4; ++j) acc[j] = rb2[e0 + j];
    for (int i = 0; i < 256; ++i) {
      float hv = h1[bl * 256 + i];
      const float* wr = rW2 + i * 256 + e0;
      #pragma unroll
      for (int j = 0; j < 4; ++j) acc[j] += hv * wr[j];
    }
    #pragma unroll
    for (int j = 0; j < 4; ++j) { float x = acc[j]; h2[bl * 256 + e0 + j] = 0.5f * x * (1.f + erff(x * 0.70710678118f)); }
  }
  __syncthreads();
  if (t < 160) {
    int bl = t / 40, j = t % 40;
    const float* W; float bs; int col, stride;
    if (j < 24)      { W = vW; col = j;      stride = 24; bs = vb[j]; }
    else if (j < 32) { W = mW; col = j - 24; stride = 8;  bs = mb[j - 24]; }
    else             { W = gW; col = j - 32; stride = 8;  bs = gb[j - 32]; }
    float acc = bs;
    for (int i = 0; i < 256; ++i) acc += h2[bl * 256 + i] * W[i * stride + col];
    lgt[bl * 40 + j] = acc;
  }
  __syncthreads();
  if (t < 4) {
    int b = bb + t;
    const float* L = &lgt[t * 40];
    #pragma unroll
    for (int hh = 0; hh < 8; ++hh) {
      float a0 = L[hh * 3], a1 = L[hh * 3 + 1], a2v = L[hh * 3 + 2];
      float m = fmaxf(a0, fmaxf(a1, a2v));
      float x0 = expf(a0 - m), x1 = expf(a1 - m), x2 = expf(a2v - m);
      float inv = 1.f / (x0 + x1 + x2);
      pi[b * 24 + hh * 3 + 0] = x0 * inv;
      pi[b * 24 + hh * 3 + 1] = x1 * inv;
      pi[b * 24 + hh * 3 + 2] = x2 * inv;
      beta_o[b * 8 + hh] = 1.f / (1.f + expf(-L[24 + hh]));
    }
    float m = L[32];
    #pragma unroll
    for (int hh = 1; hh < 8; ++hh) m = fmaxf(m, L[32 + hh]);
    float s = 0.f, ex[8];
    #pragma unroll
    for (int hh = 0; hh < 8; ++hh) { ex[hh] = expf(L[32 + hh] - m); s += ex[hh]; }
    float inv = 1.f / s;
    #pragma unroll
    for (int hh = 0; hh < 8; ++hh) gate_o[b * 8 + hh] = ex[hh] * inv;
  }
}

// ---------------------------------------------------------------------------
// K4: pi-mixture + cross-view attention + output. Block = 4 b's, fp32.
// kc/vc never materialized:  s2 = (qc @ cWk^T) . vt ;  cr = (sum_v a2*vt) @ cWv.
// ---------------------------------------------------------------------------
__global__ __launch_bounds__(256) void k4_cross(
    const float* __restrict__ vtg, const float* __restrict__ pig,
    const float* __restrict__ betag, const float* __restrict__ gateg,
    const float* __restrict__ cWq, const float* __restrict__ cWk,
    const float* __restrict__ cWv, const float* __restrict__ cWo,
    float* __restrict__ out)
{
  __shared__ float smem[12544];
  float* vts   = smem;          // 6144: [4][8][3][64]
  float* mixs  = smem + 6144;   // 2048
  float* buf1  = smem + 8192;   // 2048: qc, then y
  float* buf2  = smem + 10240;  // 2048: w,  then cr
  float* a2s   = smem + 12288;  // 96
  float* pis   = smem + 12384;  // 96
  float* betas = smem + 12480;  // 32
  float* gates = smem + 12512;  // 32

  int t = threadIdx.x, bblk = blockIdx.x * 4;
  {
    const float4* src = (const float4*)(vtg + (long)bblk * 1536);
    #pragma unroll
    for (int r = 0; r < 6; ++r) ((float4*)vts)[r * 256 + t] = src[r * 256 + t];
    if (t < 96) pis[t] = pig[bblk * 24 + t];
    if (t < 32) { betas[t] = betag[bblk * 8 + t]; gates[t] = gateg[bblk * 8 + t]; }
  }
  __syncthreads();
  int bl = t >> 6, hh = (t >> 3) & 7, e0 = (t & 7) * 8;
  const float* vbh = &vts[(bl * 8 + hh) * 192];
  { // mix
    float p0 = pis[bl * 24 + hh * 3], p1 = pis[bl * 24 + hh * 3 + 1], p2 = pis[bl * 24 + hh * 3 + 2];
    #pragma unroll
    for (int j = 0; j < 8; ++j) {
      int e = e0 + j;
      mixs[(bl * 8 + hh) * 64 + e] = p0 * vbh[e] + p1 * vbh[64 + e] + p2 * vbh[128 + e];
    }
  }
  __syncthreads();
  { // qc (scaled by 1/8) -> buf1
    float acc[8] = {0.f,0.f,0.f,0.f,0.f,0.f,0.f,0.f};
    const float* M = &mixs[(bl * 8 + hh) * 64];
    for (int d = 0; d < 64; ++d) {
      float mv = M[d];
      const float* wr = &cWq[(hh * 64 + d) * 64 + e0];
      #pragma unroll
      for (int j = 0; j < 8; ++j) acc[j] += mv * wr[j];
    }
    #pragma unroll
    for (int j = 0; j < 8; ++j) buf1[(bl * 8 + hh) * 64 + e0 + j] = acc[j] * 0.125f;
  }
  __syncthreads();
  { // w = cWk @ qc -> buf2
    const float* Q = &buf1[(bl * 8 + hh) * 64];
    #pragma unroll
    for (int d2 = 0; d2 < 8; ++d2) {
      const float* wr = &cWk[(hh * 64 + e0 + d2) * 64];
      float a = 0.f;
      for (int e = 0; e < 64; ++e) a += wr[e] * Q[e];
      buf2[(bl * 8 + hh) * 64 + e0 + d2] = a;
    }
  }
  __syncthreads();
  if (t < 32) { // s2 + a2
    int b2 = t >> 3, h2 = t & 7;
    const float* Wd = &buf2[(b2 * 8 + h2) * 64];
    const float* vb2 = &vts[(b2 * 8 + h2) * 192];
    float s[3];
    #pragma unroll
    for (int v3 = 0; v3 < 3; ++v3) {
      float a = 0.f;
      for (int d = 0; d < 64; ++d) a += Wd[d] * vb2[v3 * 64 + d];
      s[v3] = a + logf(pis[b2 * 24 + h2 * 3 + v3] + 1e-6f);
    }
    float m = fmaxf(s[0], fmaxf(s[1], s[2]));
    float x0 = expf(s[0] - m), x1 = expf(s[1] - m), x2 = expf(s[2] - m);
    float inv = 1.f / (x0 + x1 + x2);
    a2s[(b2 * 8 + h2) * 3 + 0] = x0 * inv;
    a2s[(b2 * 8 + h2) * 3 + 1] = x1 * inv;
    a2s[(b2 * 8 + h2) * 3 + 2] = x2 * inv;
  }
  __syncthreads();
  { // y = sum_v a2*vt -> buf1 (qc dead)
    float a0 = a2s[(bl * 8 + hh) * 3], a1 = a2s[(bl * 8 + hh) * 3 + 1], a2v = a2s[(bl * 8 + hh) * 3 + 2];
    #pragma unroll
    for (int j = 0; j < 8; ++j) {
      int e = e0 + j;
      buf1[(bl * 8 + hh) * 64 + e] = a0 * vbh[e] + a1 * vbh[64 + e] + a2v * vbh[128 + e];
    }
  }
  __syncthreads();
  { // cr = y @ cWv -> buf2 (w dead)
    float acc[8] = {0.f,0.f,0.f,0.f,0.f,0.f,0.f,0.f};
    const float* Y = &buf1[(bl * 8 + hh) * 64];
    for (int d = 0; d < 64; ++d) {
      float yv = Y[d];
      const float* wr = &cWv[(hh * 64 + d) * 64 + e0];
      #pragma unroll
      for (int j = 0; j < 8; ++j) acc[j] += yv * wr[j];
    }
    #pragma unroll
    for (int j = 0; j < 8; ++j) buf2[(bl * 8 + hh) * 64 + e0 + j] = acc[j];
  }
  __syncthreads();
  { // out = gate*(beta*(cr@cWo) + (1-beta)*mix)
    float acc[8] = {0.f,0.f,0.f,0.f,0.f,0.f,0.f,0.f};
    const float* C2 = &buf2[(bl * 8 + hh) * 64];
    for (int d = 0; d < 64; ++d) {
      float cv = C2[d];
      const float* wr = &cWo[(hh * 64 + d) * 64 + e0];
      #pragma unroll
      for (int j = 0; j < 8; ++j) acc[j] += cv * wr[j];
    }
    float bt = betas[bl * 8 + hh], gt = gates[bl * 8 + hh];
    const float* M = &mixs[(bl * 8 + hh) * 64];
    #pragma unroll
    for (int j = 0; j < 8; ++j)
      out[((long)(bblk + bl) * 8 + hh) * 64 + e0 + j] = gt * (bt * acc[j] + (1.f - bt) * M[e0 + j]);
  }
}

// ---------------------------------------------------------------------------
extern "C" void kernel_launch(void* const* d_in, const int* in_sizes, int n_in,
                              void* d_out, int out_size, void* d_ws, size_t ws_size,
                              hipStream_t stream) {
  const float* x_anchor    = (const float*)d_in[0];
  const float* x_neighbors = (const float*)d_in[1];
  const float* edge_w      = (const float*)d_in[2];
  const float* g           = (const float*)d_in[3];
  const float* aW  = (const float*)d_in[4];
  const float* ab  = (const float*)d_in[5];
  const float* ag  = (const float*)d_in[6];
  const float* abeta = (const float*)d_in[7];
  const float* nW  = (const float*)d_in[8];
  const float* nb  = (const float*)d_in[9];
  const float* ng  = (const float*)d_in[10];
  const float* nbeta = (const float*)d_in[11];
  const float* Wq  = (const float*)d_in[12];
  const float* Wk  = (const float*)d_in[13];
  const float* Wv  = (const float*)d_in[14];
  const float* Wo  = (const float*)d_in[15];
  const float* gls = (const float*)d_in[16];
  const float* cWq = (const float*)d_in[17];
  const float* cWk = (const float*)d_in[18];
  const float* cWv = (const float*)d_in[19];
  const float* cWo = (const float*)d_in[20];
  const float* rW1 = (const float*)d_in[21];
  const float* rb1 = (const float*)d_in[22];
  const float* rW2 = (const float*)d_in[23];
  const float* rb2 = (const float*)d_in[24];
  const float* vW  = (const float*)d_in[25];
  const float* vb  = (const float*)d_in[26];
  const float* mW  = (const float*)d_in[27];
  const float* mb  = (const float*)d_in[28];
  const float* gW  = (const float*)d_in[29];
  const float* gb  = (const float*)d_in[30];

  // workspace carve-up
  char* p = (char*)d_ws;
  u16* nWt = (u16*)p;  p += 786432;
  u16* aWt = (u16*)p;  p += 786432;
  u16* Wkt = (u16*)p;  p += 196608;
  u16* Wvt = (u16*)p;  p += 196608;
  float* ha   = (float*)p; p += 12582912;
  float* vtb  = (float*)p; p += 12582912;
  float* pib  = (float*)p; p += 196608;
  float* betb = (float*)p; p += 65536;
  float* gatb = (float*)p; p += 65536;
  size_t fixed = (size_t)(p - (char*)d_ws);
  // chunking over b so the hn intermediate (bf16, 98304 B per b) fits in ws
  int C = 1;
  while (C < 128 && fixed + (size_t)(2048 / C) * 98304 > ws_size) C <<= 1;
  int Bc = 2048 / C;
  u16* hnb = (u16*)p;

  k0_prep<<<1920, 256, 0, stream>>>(nW, aW, Wk, Wv, nWt, aWt, Wkt, Wvt);
  // anchor encoder: ha (fp32)
  k1_gemm_ln<<<dim3(64, 3), 256, 0, stream>>>(x_anchor, aWt, ab, ag, abeta,
                                              (u16*)nullptr, ha, 1, 0, Bc);
  k3_router<<<512, 256, 0, stream>>>(g, rW1, rb1, rW2, rb2, vW, vb, mW, mb, gW, gb,
                                     pib, betb, gatb);
  for (int c = 0; c < C; ++c) {
    int b0 = c * Bc;
    k1_gemm_ln<<<dim3(Bc, 3), 256, 0, stream>>>(x_neighbors, nWt, nb, ng, nbeta,
                                                hnb, (float*)nullptr, 0, b0, Bc);
    k2_attn<<<dim3(Bc / 4, 8, 3), 256, 0, stream>>>(hnb, ha, Wkt, Wvt, Wq, Wo,
                                                    edge_w, gls, vtb, b0, Bc);
  }
  k4_cross<<<512, 256, 0, stream>>>(vtb, pib, betb, gatb, cWq, cWk, cWv, cWo,
                                    (float*)d_out);
}

// Round 4
// 748.589 us; speedup vs baseline: 1.2627x; 1.0482x over previous
//
#include <hip/hip_runtime.h>

// Problem constants
#define B_   2048
#define V_   3
#define K_   32
#define DIN_ 256
#define H_   8
#define DH_  64
#define REP_ 512

typedef unsigned short u16;
typedef unsigned int   u32;
typedef __bf16 bf8 __attribute__((ext_vector_type(8)));
typedef float  f4  __attribute__((ext_vector_type(4)));

static __device__ __forceinline__ u16 f2bf(float f) {
  union { float f; u32 i; } x; x.f = f;
  u32 r = (x.i + 0x7FFFu + ((x.i >> 16) & 1u)) >> 16;   // RNE
  return (u16)r;
}
static __device__ __forceinline__ float bf2f(u16 u) {
  union { u32 i; float f; } x; x.i = ((u32)u) << 16;
  return x.f;
}
static __device__ __forceinline__ float bflo(u32 q) {
  union { u32 i; float f; } x; x.i = q << 16; return x.f;
}
static __device__ __forceinline__ float bfhi(u32 q) {
  union { u32 i; float f; } x; x.i = q & 0xffff0000u; return x.f;
}

// async global->LDS DMA, 16 B per lane; lane i lands at base + i*16
static __device__ __forceinline__ void gl2lds16(const u16* g, u16* l) {
  __builtin_amdgcn_global_load_lds(
      (const __attribute__((address_space(1))) unsigned int*)(g),
      (__attribute__((address_space(3))) unsigned int*)(l), 16, 0, 0);
}

// ---------------------------------------------------------------------------
// K0: weight prep.
//  nWt/aWt: [v][kt(8)] x 32KB "LDS image": element at hw index
//    n*32 + (c ^ ((n>>1)&3))*8 + m   equals  W[k = kt*32 + c*8 + m][n]  (bf16)
//  so global_load_lds with linear lane mapping reproduces the swizzled LDS
//  layout the MFMA B-fragment reads expect.  (verified passing in round 3)
//  Wvt: [v][h][e(64)][d(64)] bf16 (transposed: B-operand layout)
// ---------------------------------------------------------------------------
__global__ __launch_bounds__(256) void k0_prep(
    const float* __restrict__ nW, const float* __restrict__ aW,
    const float* __restrict__ Wv,
    u16* __restrict__ nWt, u16* __restrict__ aWt,
    u16* __restrict__ Wvt)
{
  int id = blockIdx.x * 256 + threadIdx.x;
  if (id < 393216) {                       // 3*8*512*32
    int v  = id / 131072, r  = id % 131072;
    int kt = r / 16384,   r2 = r % 16384;
    int n  = r2 >> 5;
    int s  = (r2 >> 3) & 3;
    int m  = r2 & 7;
    int c  = s ^ ((n >> 1) & 3);
    int k  = kt * 32 + c * 8 + m;
    int src = (v * 256 + k) * 512 + n;
    nWt[id] = f2bf(nW[src]);
    aWt[id] = f2bf(aW[src]);
  } else {
    int j = id - 393216;                   // < 98304 = 3*8*64*64
    int vh = j / 4096, r = j % 4096;
    int e = r / 64, d = r % 64;
    int src = (vh * 64 + d) * 64 + e;
    Wvt[j] = f2bf(Wv[src]);
  }
}

// ---------------------------------------------------------------------------
// K0b: Wqk[vh][d][e] = sum_c Wq[vh][d][c] * Wk[vh][e][c]   (fp32)
// Folds the q-projection and K-projection of the per-view attention:
//   q.K = (ha Wq).(hn Wk) = ha (Wq Wk^T) hn^T
// One block per (v,h); 24 blocks.
// ---------------------------------------------------------------------------
__global__ __launch_bounds__(256) void k0_wqk(
    const float* __restrict__ Wq, const float* __restrict__ Wk,
    float* __restrict__ Wqk)
{
  int vh = blockIdx.x, t = threadIdx.x;
  __shared__ float wq[4096], wkT[4096];
  #pragma unroll
  for (int i = 0; i < 16; ++i) {
    int idx = i * 256 + t;
    wq[idx] = Wq[(long)vh * 4096 + idx];
    int e = idx >> 6, c = idx & 63;
    wkT[c * 64 + e] = Wk[(long)vh * 4096 + e * 64 + c];
  }
  __syncthreads();
  int d = t >> 2, e0 = (t & 3) * 16;
  float acc[16];
  #pragma unroll
  for (int j = 0; j < 16; ++j) acc[j] = 0.f;
  for (int c = 0; c < 64; ++c) {
    float a = wq[d * 64 + c];
    const float* wr = &wkT[c * 64 + e0];
    #pragma unroll
    for (int j = 0; j < 16; ++j) acc[j] += a * wr[j];
  }
  #pragma unroll
  for (int j = 0; j < 16; ++j) Wqk[(long)vh * 4096 + d * 64 + e0 + j] = acc[j];
}

// ---------------------------------------------------------------------------
// K1 v4: [64 x 512] = [64 x 256] @ [256 x 512] bf16 MFMA GEMM + bias + LN.
// Round-1 structure (M=64, 512 thr, 64 KB union LDS, 2 blocks/CU) with:
//  - B staged per kt via global_load_lds width=16 from pre-swizzled image
//    (no VGPR round-trip, no VALU addressing in the staging path)
//  - A staged ONCE (32 KB) before the loop
//  - LN epilogue reads via ds_read_b128 instead of scalar u16
// mode 0 (neighbors): block = 2 b's x 32 k for one v; out hn bf16
//   head-major [v][h][b_local][k][64].
// mode 1 (anchor): block = 64 b's for one v; out ha fp32 [b][v][512].
// ---------------------------------------------------------------------------
union K1Smem {
  struct { u16 A[64 * 256]; u16 B[16384]; } p;   // 32 KB + 32 KB
  u16 S[64 * 512];                               // 64 KB (epilogue)
};

__global__ __launch_bounds__(512, 4) void k1_gemm_ln(
    const float* __restrict__ X,      // x_neighbors or x_anchor
    const u16*   __restrict__ Wt,     // nWt or aWt (swizzled LDS-image tiles)
    const float* __restrict__ bias,   // nb or ab   [V][512]
    const float* __restrict__ gamma,  // ng or ag
    const float* __restrict__ betap,  // nbeta or abeta
    u16*   __restrict__ hn,           // out (mode 0)
    float* __restrict__ ha,           // out (mode 1)
    int mode, int b0, int Bc)
{
  __shared__ K1Smem sm;
  const int v = blockIdx.y, blk = blockIdx.x, t = threadIdx.x;
  const int w = t >> 6, l = t & 63, lm = l & 15, lg = l >> 4;
  const int wm = w & 1, wn = w >> 1;

  // bias columns for this wave's 128-col slice
  float bcol[8];
  #pragma unroll
  for (int tn = 0; tn < 8; ++tn) bcol[tn] = bias[v * 512 + wn * 128 + tn * 16 + lm];

  // ---- stage A once (fp32 -> bf16, XOR-swizzled rows) ----
  {
    int row = t >> 3;
    int cbase = (t & 7) * 32;
    long grow;
    if (mode == 0) { int b = b0 + blk * 2 + (row >> 5); grow = ((long)(b * 3 + v) * 32 + (row & 31)) * 256; }
    else           { int b = blk * 64 + row;            grow = (long)(b * 3 + v) * 256; }
    const float4* src = (const float4*)(X + grow + cbase);
    int sw = row & 7;
    #pragma unroll
    for (int j = 0; j < 8; ++j) {
      float4 f = src[j];
      int col = cbase + j * 4;
      int c = col >> 3, m = col & 7;
      ushort4 u;
      u.x = f2bf(f.x); u.y = f2bf(f.y); u.z = f2bf(f.z); u.w = f2bf(f.w);
      *(ushort4*)&sm.p.A[row * 256 + ((c ^ sw) << 3) + m] = u;
    }
  }

  f4 acc[2][8];
  #pragma unroll
  for (int i = 0; i < 2; ++i)
    #pragma unroll
    for (int j = 0; j < 8; ++j) { f4 z = {0.f, 0.f, 0.f, 0.f}; acc[i][j] = z; }

  // ---- K loop: 2 barriers/kt, B via async DMA (m97 pattern) ----
  const u16* Wbase = Wt + (long)v * 8 * 16384;
  for (int kt = 0; kt < 8; ++kt) {
    __syncthreads();                       // all waves done reading prev B
    {   // DMA B tile kt: 512 lanes x 16 B x 4 rounds = 32 KB
      const u16* gp = Wbase + (long)kt * 16384 + t * 8;
      u16* lp = &sm.p.B[t * 8];
      #pragma unroll
      for (int r = 0; r < 4; ++r) gl2lds16(gp + r * 4096, lp + r * 4096);
    }
    __syncthreads();                       // vmcnt+lgkm drain: B (and A) ready
    bf8 af[2];
    #pragma unroll
    for (int tm = 0; tm < 2; ++tm) {
      int row = wm * 32 + tm * 16 + lm;
      int c = kt * 4 + lg;
      af[tm] = *(const bf8*)&sm.p.A[row * 256 + ((c ^ (row & 7)) << 3)];
    }
    #pragma unroll
    for (int tn = 0; tn < 8; ++tn) {
      int n = wn * 128 + tn * 16 + lm;
      bf8 bv = *(const bf8*)&sm.p.B[n * 32 + ((lg ^ ((n >> 1) & 3)) << 3)];
      acc[0][tn] = __builtin_amdgcn_mfma_f32_16x16x32_bf16(af[0], bv, acc[0][tn], 0, 0, 0);
      acc[1][tn] = __builtin_amdgcn_mfma_f32_16x16x32_bf16(af[1], bv, acc[1][tn], 0, 0, 0);
    }
  }
  __syncthreads();

  // ---- dump z = acc + bias into S (64x512 bf16, XOR-swizzled) ----
  #pragma unroll
  for (int tm = 0; tm < 2; ++tm)
    #pragma unroll
    for (int tn = 0; tn < 8; ++tn) {
      int col = wn * 128 + tn * 16 + lm;
      int c = col >> 3, m = col & 7;
      #pragma unroll
      for (int r = 0; r < 4; ++r) {
        int row = wm * 32 + tm * 16 + lg * 4 + r;
        sm.S[row * 512 + ((c ^ (row & 7)) << 3) + m] = f2bf(acc[tm][tn][r] + bcol[tn]);
      }
    }
  __syncthreads();

  // ---- LayerNorm + writeout: 8 threads/row, b128 LDS reads ----
  {
    int row = t >> 3, ch = t & 7, sw = row & 7;
    float s1 = 0.f, s2 = 0.f;
    #pragma unroll
    for (int j = 0; j < 8; ++j) {
      int c = j * 8 + ch;
      uint4 q = *(const uint4*)&sm.S[row * 512 + ((c ^ sw) << 3)];
      float x0 = bflo(q.x), x1 = bfhi(q.x), x2 = bflo(q.y), x3 = bfhi(q.y);
      float x4 = bflo(q.z), x5 = bfhi(q.z), x6 = bflo(q.w), x7 = bfhi(q.w);
      s1 += ((x0 + x1) + (x2 + x3)) + ((x4 + x5) + (x6 + x7));
      s2 += ((x0*x0 + x1*x1) + (x2*x2 + x3*x3)) + ((x4*x4 + x5*x5) + (x6*x6 + x7*x7));
    }
    #pragma unroll
    for (int d = 1; d < 8; d <<= 1) { s1 += __shfl_xor(s1, d, 64); s2 += __shfl_xor(s2, d, 64); }
    float mu = s1 * (1.f / 512.f);
    float var = s2 * (1.f / 512.f) - mu * mu;
    float rs = rsqrtf(var + 1e-5f);
    #pragma unroll
    for (int j = 0; j < 8; ++j) {
      int c = j * 8 + ch;
      uint4 q = *(const uint4*)&sm.S[row * 512 + ((c ^ sw) << 3)];
      int col0 = c * 8;
      float4 g0 = *(const float4*)&gamma[v * 512 + col0];
      float4 g1 = *(const float4*)&gamma[v * 512 + col0 + 4];
      float4 e0 = *(const float4*)&betap[v * 512 + col0];
      float4 e1 = *(const float4*)&betap[v * 512 + col0 + 4];
      float y0 = (bflo(q.x) - mu) * rs * g0.x + e0.x;
      float y1 = (bfhi(q.x) - mu) * rs * g0.y + e0.y;
      float y2 = (bflo(q.y) - mu) * rs * g0.z + e0.z;
      float y3 = (bfhi(q.y) - mu) * rs * g0.w + e0.w;
      float y4 = (bflo(q.z) - mu) * rs * g1.x + e1.x;
      float y5 = (bfhi(q.z) - mu) * rs * g1.y + e1.y;
      float y6 = (bflo(q.w) - mu) * rs * g1.z + e1.z;
      float y7 = (bfhi(q.w) - mu) * rs * g1.w + e1.w;
      if (mode == 0) {
        // j == head, ch*8 == element offset within head
        uint4 q4;
        q4.x = (u32)f2bf(y0) | ((u32)f2bf(y1) << 16);
        q4.y = (u32)f2bf(y2) | ((u32)f2bf(y3) << 16);
        q4.z = (u32)f2bf(y4) | ((u32)f2bf(y5) << 16);
        q4.w = (u32)f2bf(y6) | ((u32)f2bf(y7) << 16);
        int bl_ = blk * 2 + (row >> 5), krow = row & 31;
        u16* dst = hn + (((long)(v * 8 + j) * Bc + bl_) * 32 + krow) * 64 + ch * 8;
        *(uint4*)dst = q4;
      } else {
        int b = blk * 64 + row;
        float* dst = ha + (long)(b * 3 + v) * 512 + col0;
        float4 w0, w1;
        w0.x = y0; w0.y = y1; w0.z = y2; w0.w = y3;
        w1.x = y4; w1.y = y5; w1.z = y6; w1.w = y7;
        *(float4*)dst = w0;
        *(float4*)(dst + 4) = w1;
      }
    }
  }
}

// ---------------------------------------------------------------------------
// K2 v3: per (v, h, group of 4 b's): V projection via MFMA (1 b per wave),
// scores via folded Wqk (no K projection!), softmax, o from accumulators,
// Wo + residual, writes view_tokens [B][H][V][64].
// ---------------------------------------------------------------------------
__global__ __launch_bounds__(256, 2) void k2_attn(
    const u16*   __restrict__ hn,     // [V][H][Bc][K][64] bf16
    const float* __restrict__ ha,     // [B][V][512] f32
    const u16*   __restrict__ Wvt,    // [V][H][64][64] bf16 transposed
    const float* __restrict__ Wqk,    // [V][H][64][64] f32 (folded Wq Wk^T)
    const float* __restrict__ Wo,     // [V][H][64][64] f32
    const float* __restrict__ ew,     // [B][V][K]
    const float* __restrict__ gls,    // [V][H]
    float* __restrict__ vt,           // [B][H][V][64]
    int b0, int Bc)
{
  const int v = blockIdx.z, h = blockIdx.y;
  const int bL0 = blockIdx.x * 4;
  const int t = threadIdx.x;
  __shared__ u16 A[128 * 72];         // hn slice (4b x 32k rows), stride 72
  __shared__ u16 Wv_s[64 * 72];
  __shared__ float t_s[4 * 64], ha_s[4 * 64], attn_s[4 * 32], o_s[4 * 64];

  // stage hn (16 KB contiguous): 128 rows x 64 d
  {
    const uint4* src = (const uint4*)(hn + ((long)(v * 8 + h) * Bc + bL0) * 2048);
    int r = t >> 1, half = t & 1;
    #pragma unroll
    for (int i = 0; i < 4; ++i) {
      uint4 d = src[r * 8 + half * 4 + i];
      *(uint4*)&A[r * 72 + half * 32 + i * 8] = d;
    }
  }
  // stage Wvt
  {
    const uint4* sv = (const uint4*)(Wvt + (long)(v * 8 + h) * 4096);
    #pragma unroll
    for (int i = 0; i < 2; ++i) {
      int idx = i * 256 + t;
      int n = idx >> 3, k8 = (idx & 7) * 8;
      *(uint4*)&Wv_s[n * 72 + k8] = sv[idx];
    }
  }
  // stage ha head slice (4 b x 64 e)
  {
    int b = t >> 6, e = t & 63;
    ha_s[t] = ha[((long)(b0 + bL0 + b) * 3 + v) * 512 + h * 64 + e];
  }
  __syncthreads();

  const int w = t >> 6, l = t & 63, lm = l & 15, lg = l >> 4;
  f4 aV[2][4];
  #pragma unroll
  for (int i = 0; i < 2; ++i)
    #pragma unroll
    for (int j = 0; j < 4; ++j) { f4 z = {0.f, 0.f, 0.f, 0.f}; aV[i][j] = z; }

  // V projection: wave w owns b = w (rows w*32 .. w*32+31)
  #pragma unroll
  for (int ks = 0; ks < 2; ++ks) {
    int ko = ks * 32 + lg * 8;
    bf8 af[2];
    #pragma unroll
    for (int tm = 0; tm < 2; ++tm) af[tm] = *(const bf8*)&A[(w * 32 + tm * 16 + lm) * 72 + ko];
    #pragma unroll
    for (int tn = 0; tn < 4; ++tn) {
      bf8 bv = *(const bf8*)&Wv_s[(tn * 16 + lm) * 72 + ko];
      #pragma unroll
      for (int tm = 0; tm < 2; ++tm)
        aV[tm][tn] = __builtin_amdgcn_mfma_f32_16x16x32_bf16(af[tm], bv, aV[tm][tn], 0, 0, 0);
    }
  }

  // t = (ha @ Wqk) * 1/sqrt(DH)   (scores = t . hn)
  {
    const float* wqk = Wqk + (long)(v * 8 + h) * 4096;
    int b = t >> 6, e = t & 63;
    float acc = 0.f;
    for (int d = 0; d < 64; ++d) acc += ha_s[b * 64 + d] * wqk[d * 64 + e];
    t_s[t] = acc * 0.125f;
  }
  __syncthreads();

  // scores + softmax (4 b x 32 k = 128 threads); hn read b128 from A
  if (t < 128) {
    int b = t >> 5, k = t & 31;
    float x = gls[v * 8 + h];
    float gsc = (x > 20.f) ? x : log1pf(expf(x));
    float s = 0.f;
    const u16* kr = &A[(b * 32 + k) * 72];
    const float* tb = &t_s[b * 64];
    #pragma unroll
    for (int j = 0; j < 8; ++j) {
      uint4 q = *(const uint4*)(kr + j * 8);
      const float* tj = tb + j * 8;
      s += tj[0] * bflo(q.x) + tj[1] * bfhi(q.x)
         + tj[2] * bflo(q.y) + tj[3] * bfhi(q.y)
         + tj[4] * bflo(q.z) + tj[5] * bfhi(q.z)
         + tj[6] * bflo(q.w) + tj[7] * bfhi(q.w);
    }
    float e_w = ew[((long)(b0 + bL0 + b) * 3 + v) * 32 + k];
    s += gsc * logf(e_w + 1e-6f);
    float m = s;
    #pragma unroll
    for (int d = 1; d < 32; d <<= 1) m = fmaxf(m, __shfl_xor(m, d, 64));
    float exs = expf(s - m), sum = exs;
    #pragma unroll
    for (int d = 1; d < 32; d <<= 1) sum += __shfl_xor(sum, d, 64);
    attn_s[b * 32 + k] = exs / sum;
  }
  __syncthreads();

  // o = attn @ V, straight from accumulators (wave w -> b = w)
  {
    float p[4] = {0.f, 0.f, 0.f, 0.f};
    #pragma unroll
    for (int tm = 0; tm < 2; ++tm)
      #pragma unroll
      for (int r = 0; r < 4; ++r) {
        int k = tm * 16 + lg * 4 + r;
        float a = attn_s[w * 32 + k];
        #pragma unroll
        for (int tn = 0; tn < 4; ++tn) p[tn] += a * aV[tm][tn][r];
      }
    #pragma unroll
    for (int tn = 0; tn < 4; ++tn) {
      float x = p[tn];
      x += __shfl_xor(x, 16, 64);
      x += __shfl_xor(x, 32, 64);
      if (l < 16) o_s[w * 64 + tn * 16 + lm] = x;
    }
  }
  __syncthreads();

  // out = o @ Wo + ha (residual), write view_tokens
  {
    const float* wo = Wo + (long)(v * 8 + h) * 4096;
    int b = t >> 6, e = t & 63;
    float acc = ha_s[b * 64 + e];
    for (int d = 0; d < 64; ++d) acc += o_s[b * 64 + d] * wo[d * 64 + e];
    vt[(((long)(b0 + bL0 + b) * 8 + h) * 3 + v) * 64 + e] = acc;
  }
}

// ---------------------------------------------------------------------------
// K3: router MLP (fp32). Block = 4 b's (512 blocks -> full GPU).
// ---------------------------------------------------------------------------
__global__ __launch_bounds__(256) void k3_router(
    const float* __restrict__ g, const float* __restrict__ rW1, const float* __restrict__ rb1,
    const float* __restrict__ rW2, const float* __restrict__ rb2,
    const float* __restrict__ vW, const float* __restrict__ vb,
    const float* __restrict__ mW, const float* __restrict__ mb,
    const float* __restrict__ gW, const float* __restrict__ gb,
    float* __restrict__ pi, float* __restrict__ beta_o, float* __restrict__ gate_o)
{
  __shared__ float gs[4 * 128], h1[4 * 256], h2[4 * 256], lgt[4 * 40];
  int t = threadIdx.x, bb = blockIdx.x * 4;
  #pragma unroll
  for (int r = 0; r < 2; ++r) { int idx = r * 256 + t; gs[idx] = g[(long)bb * 128 + idx]; }
  __syncthreads();
  {
    int bl = t >> 6, e0 = (t & 63) * 4;
    float acc[4];
    #pragma unroll
    for (int j = 0; j < 4; ++j) acc[j] = rb1[e0 + j];
    for (int i = 0; i < 128; ++i) {
      float gv = gs[bl * 128 + i];
      const float* wr = rW1 + i * 256 + e0;
      #pragma unroll
      for (int j = 0; j < 4; ++j) acc[j] += gv * wr[j];
    }
    #pragma unroll
    for (int j = 0; j < 4; ++j) { float x = acc[j]; h1[bl * 256 + e0 + j] = 0.5f * x * (1.f + erff(x * 0.70710678118f)); }
  }
  __syncthreads();
  {
    int bl = t >> 6, e0 = (t & 63) * 4;
    float acc[4];
    #pragma unroll
    for (int j = 0; j < 4; ++j) acc[j] = rb2[e0 + j];
    for (int i = 0; i < 256; ++i) {
      float hv = h1[bl * 256 + i];
      const float* wr = rW2 + i * 256 + e0;
      #pragma unroll
      for (int j = 0; j < 4; ++j) acc[j] += hv * wr[j];
    }
    #pragma unroll
    for (int j = 0; j < 4; ++j) { float x = acc[j]; h2[bl * 256 + e0 + j] = 0.5f * x * (1.f + erff(x * 0.70710678118f)); }
  }
  __syncthreads();
  if (t < 160) {
    int bl = t / 40, j = t % 40;
    const float* W; float bs; int col, stride;
    if (j < 24)      { W = vW; col = j;      stride = 24; bs = vb[j]; }
    else if (j < 32) { W = mW; col = j - 24; stride = 8;  bs = mb[j - 24]; }
    else             { W = gW; col = j - 32; stride = 8;  bs = gb[j - 32]; }
    float acc = bs;
    for (int i = 0; i < 256; ++i) acc += h2[bl * 256 + i] * W[i * stride + col];
    lgt[bl * 40 + j] = acc;
  }
  __syncthreads();
  if (t < 4) {
    int b = bb + t;
    const float* L = &lgt[t * 40];
    #pragma unroll
    for (int hh = 0; hh < 8; ++hh) {
      float a0 = L[hh * 3], a1 = L[hh * 3 + 1], a2v = L[hh * 3 + 2];
      float m = fmaxf(a0, fmaxf(a1, a2v));
      float x0 = expf(a0 - m), x1 = expf(a1 - m), x2 = expf(a2v - m);
      float inv = 1.f / (x0 + x1 + x2);
      pi[b * 24 + hh * 3 + 0] = x0 * inv;
      pi[b * 24 + hh * 3 + 1] = x1 * inv;
      pi[b * 24 + hh * 3 + 2] = x2 * inv;
      beta_o[b * 8 + hh] = 1.f / (1.f + expf(-L[24 + hh]));
    }
    float m = L[32];
    #pragma unroll
    for (int hh = 1; hh < 8; ++hh) m = fmaxf(m, L[32 + hh]);
    float s = 0.f, ex[8];
    #pragma unroll
    for (int hh = 0; hh < 8; ++hh) { ex[hh] = expf(L[32 + hh] - m); s += ex[hh]; }
    float inv = 1.f / s;
    #pragma unroll
    for (int hh = 0; hh < 8; ++hh) gate_o[b * 8 + hh] = ex[hh] * inv;
  }
}

// ---------------------------------------------------------------------------
// K4: pi-mixture + cross-view attention + output. Block = 4 b's, fp32.
// kc/vc never materialized:  s2 = (qc @ cWk^T) . vt ;  cr = (sum_v a2*vt) @ cWv.
// ---------------------------------------------------------------------------
__global__ __launch_bounds__(256) void k4_cross(
    const float* __restrict__ vtg, const float* __restrict__ pig,
    const float* __restrict__ betag, const float* __restrict__ gateg,
    const float* __restrict__ cWq, const float* __restrict__ cWk,
    const float* __restrict__ cWv, const float* __restrict__ cWo,
    float* __restrict__ out)
{
  __shared__ float smem[12544];
  float* vts   = smem;          // 6144: [4][8][3][64]
  float* mixs  = smem + 6144;   // 2048
  float* buf1  = smem + 8192;   // 2048: qc, then y
  float* buf2  = smem + 10240;  // 2048: w,  then cr
  float* a2s   = smem + 12288;  // 96
  float* pis   = smem + 12384;  // 96
  float* betas = smem + 12480;  // 32
  float* gates = smem + 12512;  // 32

  int t = threadIdx.x, bblk = blockIdx.x * 4;
  {
    const float4* src = (const float4*)(vtg + (long)bblk * 1536);
    #pragma unroll
    for (int r = 0; r < 6; ++r) ((float4*)vts)[r * 256 + t] = src[r * 256 + t];
    if (t < 96) pis[t] = pig[bblk * 24 + t];
    if (t < 32) { betas[t] = betag[bblk * 8 + t]; gates[t] = gateg[bblk * 8 + t]; }
  }
  __syncthreads();
  int bl = t >> 6, hh = (t >> 3) & 7, e0 = (t & 7) * 8;
  const float* vbh = &vts[(bl * 8 + hh) * 192];
  { // mix
    float p0 = pis[bl * 24 + hh * 3], p1 = pis[bl * 24 + hh * 3 + 1], p2 = pis[bl * 24 + hh * 3 + 2];
    #pragma unroll
    for (int j = 0; j < 8; ++j) {
      int e = e0 + j;
      mixs[(bl * 8 + hh) * 64 + e] = p0 * vbh[e] + p1 * vbh[64 + e] + p2 * vbh[128 + e];
    }
  }
  __syncthreads();
  { // qc (scaled by 1/8) -> buf1
    float acc[8] = {0.f,0.f,0.f,0.f,0.f,0.f,0.f,0.f};
    const float* M = &mixs[(bl * 8 + hh) * 64];
    for (int d = 0; d < 64; ++d) {
      float mv = M[d];
      const float* wr = &cWq[(hh * 64 + d) * 64 + e0];
      #pragma unroll
      for (int j = 0; j < 8; ++j) acc[j] += mv * wr[j];
    }
    #pragma unroll
    for (int j = 0; j < 8; ++j) buf1[(bl * 8 + hh) * 64 + e0 + j] = acc[j] * 0.125f;
  }
  __syncthreads();
  { // w = cWk @ qc -> buf2
    const float* Q = &buf1[(bl * 8 + hh) * 64];
    #pragma unroll
    for (int d2 = 0; d2 < 8; ++d2) {
      const float* wr = &cWk[(hh * 64 + e0 + d2) * 64];
      float a = 0.f;
      for (int e = 0; e < 64; ++e) a += wr[e] * Q[e];
      buf2[(bl * 8 + hh) * 64 + e0 + d2] = a;
    }
  }
  __syncthreads();
  if (t < 32) { // s2 + a2
    int b2 = t >> 3, h2 = t & 7;
    const float* Wd = &buf2[(b2 * 8 + h2) * 64];
    const float* vb2 = &vts[(b2 * 8 + h2) * 192];
    float s[3];
    #pragma unroll
    for (int v3 = 0; v3 < 3; ++v3) {
      float a = 0.f;
      for (int d = 0; d < 64; ++d) a += Wd[d] * vb2[v3 * 64 + d];
      s[v3] = a + logf(pis[b2 * 24 + h2 * 3 + v3] + 1e-6f);
    }
    float m = fmaxf(s[0], fmaxf(s[1], s[2]));
    float x0 = expf(s[0] - m), x1 = expf(s[1] - m), x2 = expf(s[2] - m);
    float inv = 1.f / (x0 + x1 + x2);
    a2s[(b2 * 8 + h2) * 3 + 0] = x0 * inv;
    a2s[(b2 * 8 + h2) * 3 + 1] = x1 * inv;
    a2s[(b2 * 8 + h2) * 3 + 2] = x2 * inv;
  }
  __syncthreads();
  { // y = sum_v a2*vt -> buf1 (qc dead)
    float a0 = a2s[(bl * 8 + hh) * 3], a1 = a2s[(bl * 8 + hh) * 3 + 1], a2v = a2s[(bl * 8 + hh) * 3 + 2];
    #pragma unroll
    for (int j = 0; j < 8; ++j) {
      int e = e0 + j;
      buf1[(bl * 8 + hh) * 64 + e] = a0 * vbh[e] + a1 * vbh[64 + e] + a2v * vbh[128 + e];
    }
  }
  __syncthreads();
  { // cr = y @ cWv -> buf2 (w dead)
    float acc[8] = {0.f,0.f,0.f,0.f,0.f,0.f,0.f,0.f};
    const float* Y = &buf1[(bl * 8 + hh) * 64];
    for (int d = 0; d < 64; ++d) {
      float yv = Y[d];
      const float* wr = &cWv[(hh * 64 + d) * 64 + e0];
      #pragma unroll
      for (int j = 0; j < 8; ++j) acc[j] += yv * wr[j];
    }
    #pragma unroll
    for (int j = 0; j < 8; ++j) buf2[(bl * 8 + hh) * 64 + e0 + j] = acc[j];
  }
  __syncthreads();
  { // out = gate*(beta*(cr@cWo) + (1-beta)*mix)
    float acc[8] = {0.f,0.f,0.f,0.f,0.f,0.f,0.f,0.f};
    const float* C2 = &buf2[(bl * 8 + hh) * 64];
    for (int d = 0; d < 64; ++d) {
      float cv = C2[d];
      const float* wr = &cWo[(hh * 64 + d) * 64 + e0];
      #pragma unroll
      for (int j = 0; j < 8; ++j) acc[j] += cv * wr[j];
    }
    float bt = betas[bl * 8 + hh], gt = gates[bl * 8 + hh];
    const float* M = &mixs[(bl * 8 + hh) * 64];
    #pragma unroll
    for (int j = 0; j < 8; ++j)
      out[((long)(bblk + bl) * 8 + hh) * 64 + e0 + j] = gt * (bt * acc[j] + (1.f - bt) * M[e0 + j]);
  }
}

// ---------------------------------------------------------------------------
extern "C" void kernel_launch(void* const* d_in, const int* in_sizes, int n_in,
                              void* d_out, int out_size, void* d_ws, size_t ws_size,
                              hipStream_t stream) {
  const float* x_anchor    = (const float*)d_in[0];
  const float* x_neighbors = (const float*)d_in[1];
  const float* edge_w      = (const float*)d_in[2];
  const float* g           = (const float*)d_in[3];
  const float* aW  = (const float*)d_in[4];
  const float* ab  = (const float*)d_in[5];
  const float* ag  = (const float*)d_in[6];
  const float* abeta = (const float*)d_in[7];
  const float* nW  = (const float*)d_in[8];
  const float* nb  = (const float*)d_in[9];
  const float* ng  = (const float*)d_in[10];
  const float* nbeta = (const float*)d_in[11];
  const float* Wq  = (const float*)d_in[12];
  const float* Wk  = (const float*)d_in[13];
  const float* Wv  = (const float*)d_in[14];
  const float* Wo  = (const float*)d_in[15];
  const float* gls = (const float*)d_in[16];
  const float* cWq = (const float*)d_in[17];
  const float* cWk = (const float*)d_in[18];
  const float* cWv = (const float*)d_in[19];
  const float* cWo = (const float*)d_in[20];
  const float* rW1 = (const float*)d_in[21];
  const float* rb1 = (const float*)d_in[22];
  const float* rW2 = (const float*)d_in[23];
  const float* rb2 = (const float*)d_in[24];
  const float* vW  = (const float*)d_in[25];
  const float* vb  = (const float*)d_in[26];
  const float* mW  = (const float*)d_in[27];
  const float* mb  = (const float*)d_in[28];
  const float* gW  = (const float*)d_in[29];
  const float* gb  = (const float*)d_in[30];

  // workspace carve-up
  char* p = (char*)d_ws;
  u16* nWt = (u16*)p;  p += 786432;
  u16* aWt = (u16*)p;  p += 786432;
  u16* Wvt = (u16*)p;  p += 196608;
  float* WqkB = (float*)p; p += 393216;
  float* ha   = (float*)p; p += 12582912;
  float* vtb  = (float*)p; p += 12582912;
  float* pib  = (float*)p; p += 196608;
  float* betb = (float*)p; p += 65536;
  float* gatb = (float*)p; p += 65536;
  size_t fixed = (size_t)(p - (char*)d_ws);
  // chunking over b so the hn intermediate (bf16, 98304 B per b) fits in ws
  int C = 1;
  while (C < 128 && fixed + (size_t)(2048 / C) * 98304 > ws_size) C <<= 1;
  int Bc = 2048 / C;
  u16* hnb = (u16*)p;

  k0_prep<<<1920, 256, 0, stream>>>(nW, aW, Wv, nWt, aWt, Wvt);
  k0_wqk<<<24, 256, 0, stream>>>(Wq, Wk, WqkB);
  // anchor encoder: ha (fp32)
  k1_gemm_ln<<<dim3(32, 3), 512, 0, stream>>>(x_anchor, aWt, ab, ag, abeta,
                                              (u16*)nullptr, ha, 1, 0, Bc);
  k3_router<<<512, 256, 0, stream>>>(g, rW1, rb1, rW2, rb2, vW, vb, mW, mb, gW, gb,
                                     pib, betb, gatb);
  for (int c = 0; c < C; ++c) {
    int b0 = c * Bc;
    k1_gemm_ln<<<dim3(Bc / 2, 3), 512, 0, stream>>>(x_neighbors, nWt, nb, ng, nbeta,
                                                    hnb, (float*)nullptr, 0, b0, Bc);
    k2_attn<<<dim3(Bc / 4, 8, 3), 256, 0, stream>>>(hnb, ha, Wvt, WqkB, Wo,
                                                    edge_w, gls, vtb, b0, Bc);
  }
  k4_cross<<<512, 256, 0, stream>>>(vtb, pib, betb, gatb, cWq, cWk, cWv, cWo,
                                    (float*)d_out);
}